// Round 16
// baseline (431.764 us; speedup 1.0000x reference)
//
#include <hip/hip_runtime.h>
#include <hip/hip_bf16.h>

#define NNODES 128000
#define NEDGES 640000
#define BB 128
#define CC 12
#define DD 128
#define NROWS (BB*CC)   // 1536
#define NSPLIT 8
#define CHUNK 125

typedef __attribute__((ext_vector_type(8))) short short8;
typedef __attribute__((ext_vector_type(4))) float f32x4;
typedef unsigned short ushort_t;

__device__ __forceinline__ unsigned pk2bf(float lo, float hi){
    union { __hip_bfloat162 h; unsigned u; } v;
    v.h = __float22bfloat162_rn(make_float2(lo, hi));
    return v.u;
}
__device__ __forceinline__ ushort_t f2bf(float f){
    union { __hip_bfloat16 h; ushort_t u; } v;
    v.h = __float2bfloat16(f);
    return v.u;
}
__device__ __forceinline__ float bfu_lo(unsigned u){
    union { unsigned u; float f; } v; v.u = u << 16; return v.f;
}
__device__ __forceinline__ float bfu_hi(unsigned u){
    union { unsigned u; float f; } v; v.u = u & 0xFFFF0000u; return v.f;
}
// accumulate 8 bf16 (one uint4) into a[o..o+7] with weight w (o compile-time)
__device__ __forceinline__ void acc8(float* a, float w, uint4 u, int o){
    a[o+0] += w*bfu_lo(u.x); a[o+1] += w*bfu_hi(u.x);
    a[o+2] += w*bfu_lo(u.y); a[o+3] += w*bfu_hi(u.y);
    a[o+4] += w*bfu_lo(u.z); a[o+5] += w*bfu_hi(u.z);
    a[o+6] += w*bfu_lo(u.w); a[o+7] += w*bfu_hi(u.w);
}

// ---------------- CSR build ----------------
__global__ __launch_bounds__(256) void count_edges(const int* __restrict__ col, int* __restrict__ cnt){
    int e = blockIdx.x*256 + threadIdx.x;
    if (e < NEDGES) atomicAdd(&cnt[col[e]], 1);
}

// scan_a also emits dinv (reads cnt anyway)
__global__ __launch_bounds__(256) void scan_a(const int* __restrict__ cnt, int* __restrict__ offs,
        int* __restrict__ bsum, float* __restrict__ dinv){
    __shared__ int tmp[256];
    int tid = threadIdx.x;
    int g = blockIdx.x*256 + tid;
    int v = cnt[g];
    dinv[g] = rsqrtf((float)v + 1.0f);
    tmp[tid] = v;
    __syncthreads();
    for (int o=1;o<256;o<<=1){
        int a = (tid>=o)? tmp[tid-o] : 0;
        __syncthreads();
        tmp[tid] += a;
        __syncthreads();
    }
    offs[g] = tmp[tid] - v;
    if (tid==255) bsum[blockIdx.x] = tmp[255];
}

__global__ __launch_bounds__(512) void scan_b(int* __restrict__ bsum, int NB){
    __shared__ int tmp[512];
    int tid = threadIdx.x;
    int v = (tid<NB)? bsum[tid] : 0;
    tmp[tid] = v;
    __syncthreads();
    for (int o=1;o<512;o<<=1){
        int a = (tid>=o)? tmp[tid-o] : 0;
        __syncthreads();
        tmp[tid] += a;
        __syncthreads();
    }
    if (tid<NB) bsum[tid] = tmp[tid] - v;
}

__global__ __launch_bounds__(256) void scan_c(int* __restrict__ offs, const int* __restrict__ bsum){
    int g = blockIdx.x*256 + threadIdx.x;
    offs[g] += bsum[g>>8];
    if (g==0) offs[NNODES] = NEDGES;
}

__global__ __launch_bounds__(256) void fill_csr(const int* __restrict__ row, const int* __restrict__ col,
        const int* __restrict__ offs, int* __restrict__ cur, const float* __restrict__ dinv,
        int2* __restrict__ ee){
    int e = blockIdx.x*256 + threadIdx.x;
    if (e >= NEDGES) return;
    int c = col[e], r = row[e];
    int p = atomicAdd(&cur[c], 1);
    int idx = offs[c] + p;
    float w = dinv[r]*dinv[c];
    ee[idx] = make_int2(r, __float_as_int(w));
}

// ---------------- all weight conversions in one kernel ----------------
__global__ __launch_bounds__(256) void conv_all(const float* __restrict__ gcn_w,
        const float* __restrict__ ca_qkv_w, const float* __restrict__ in_w,
        const float* __restrict__ caout, const float* __restrict__ ff1, const float* __restrict__ ff2,
        ushort_t* __restrict__ Wb, ushort_t* __restrict__ Wpad, ushort_t* __restrict__ Wd){
    int i = blockIdx.x*256 + threadIdx.x;   // < 233472
    if (i < 81920){
        int slot = i >> 14, off = i & 16383;
        float v = (slot < 3) ? gcn_w[slot*16384 + off]
                             : ca_qkv_w[16384 + (slot-3)*16384 + off];
        Wb[i] = f2bf(v);
    } else if (i < 86016){
        int j = i - 81920;
        int n = j >> 5, k = j & 31;
        Wpad[j] = (k < 16) ? f2bf(in_w[n*16 + k]) : (ushort_t)0;
    } else {
        int j = i - 86016;   // < 147456
        float v;
        if (j < 16384) v = caout[j];
        else if (j < 81920) v = ff1[j - 16384];
        else v = ff2[j - 81920];
        Wd[j] = f2bf(v);
    }
}

// ---------------- input projection via MFMA (swapped operands, uint2 stores) ----------------
__global__ __launch_bounds__(256) void in_proj_mfma(const float* __restrict__ x,
        const ushort_t* __restrict__ Wpad, const float* __restrict__ bias,
        ushort_t* __restrict__ hbf){
    __shared__ __align__(16) ushort_t xs[64*40];
    int tid = threadIdx.x;
    int m0 = blockIdx.x*64;
    if (tid < 128){
        short8 z = {0,0,0,0,0,0,0,0};
        *(short8*)&xs[(tid>>1)*40 + 16 + (tid&1)*8] = z;
    }
    float4 xv = *(const float4*)(x + (size_t)m0*16 + tid*4);
    uint2 pk2;
    pk2.x = pk2bf(xv.x, xv.y);
    pk2.y = pk2bf(xv.z, xv.w);
    *(uint2*)&xs[(tid>>2)*40 + (tid&3)*4] = pk2;
    __syncthreads();
    int lane = tid & 63, w = tid >> 6;
    int lr = lane & 15, hi4 = lane >> 4, lk = hi4*8;
    short8 wf[8];
    #pragma unroll
    for (int nt=0; nt<8; ++nt)
        wf[nt] = *(const short8*)&Wpad[(nt*16 + lr)*32 + lk];
    short8 a = *(const short8*)&xs[(w*16 + lr)*40 + lk];
    f32x4 acc[8];
    #pragma unroll
    for (int nt=0; nt<8; ++nt)
        acc[nt] = __builtin_amdgcn_mfma_f32_16x16x32_bf16(wf[nt], a, (f32x4){0,0,0,0}, 0, 0, 0);
    size_t m = (size_t)m0 + w*16 + lr;
    #pragma unroll
    for (int nt=0; nt<8; ++nt){
        int n0 = nt*16 + hi4*4;
        float4 bv = *(const float4*)&bias[n0];
        uint2 pk;
        pk.x = pk2bf(acc[nt][0]+bv.x, acc[nt][1]+bv.y);
        pk.y = pk2bf(acc[nt][2]+bv.z, acc[nt][3]+bv.w);
        *(uint2*)&hbf[m*128 + n0] = pk;
    }
}

// ---------------- MFMA GEMM, swapped operands (D rows = n, cols = m) --------------
__global__ __launch_bounds__(256) void gemm_mfma(const ushort_t* __restrict__ A,
        const ushort_t* __restrict__ Wb, const float* __restrict__ bias, ushort_t* __restrict__ out){
    __shared__ __align__(16) ushort_t wl[128*136];
    int tid = threadIdx.x;
    #pragma unroll
    for (int i=0;i<8;++i){
        int elem = tid*8 + i*2048;
        int row = elem >> 7, k = elem & 127;
        *(short8*)&wl[row*136 + k] = *(const short8*)&Wb[elem];
    }
    __syncthreads();
    int lane = tid & 63, wave = tid >> 6;
    int m0 = blockIdx.x*128 + wave*32;
    int lr = lane & 15, hi4 = lane >> 4;
    int lk = hi4 * 8;
    f32x4 acc[2][8];
    #pragma unroll
    for (int t=0;t<2;++t)
        #pragma unroll
        for (int nt=0;nt<8;++nt) acc[t][nt] = (f32x4){0.f,0.f,0.f,0.f};
    const ushort_t* arow0 = A + (size_t)(m0 + lr)*128 + lk;
    const ushort_t* arow1 = arow0 + 16*128;
    #pragma unroll
    for (int kc=0; kc<4; ++kc){
        short8 h0 = *(const short8*)(arow0 + kc*32);
        short8 h1 = *(const short8*)(arow1 + kc*32);
        #pragma unroll
        for (int nt=0; nt<8; ++nt){
            short8 wf = *(const short8*)&wl[(nt*16 + lr)*136 + kc*32 + lk];
            acc[0][nt] = __builtin_amdgcn_mfma_f32_16x16x32_bf16(wf, h0, acc[0][nt], 0, 0, 0);
            acc[1][nt] = __builtin_amdgcn_mfma_f32_16x16x32_bf16(wf, h1, acc[1][nt], 0, 0, 0);
        }
    }
    #pragma unroll
    for (int nt=0; nt<8; ++nt){
        int n0 = nt*16 + hi4*4;
        float b0=0.f,b1=0.f,b2=0.f,b3=0.f;
        if (bias){
            float4 bv = *(const float4*)&bias[n0];
            b0=bv.x; b1=bv.y; b2=bv.z; b3=bv.w;
        }
        #pragma unroll
        for (int t=0; t<2; ++t){
            size_t m = (size_t)m0 + t*16 + lr;
            uint2 pk;
            pk.x = pk2bf(acc[t][nt][0]+b0, acc[t][nt][1]+b1);
            pk.y = pk2bf(acc[t][nt][2]+b2, acc[t][nt][3]+b3);
            *(uint2*)&out[m*128 + n0] = pk;
        }
    }
}

// ---------------- fused K+V GEMM: A loaded once to registers, W staged twice ----------
__global__ __launch_bounds__(256) void gemm_mfma_kv(const ushort_t* __restrict__ A,
        const ushort_t* __restrict__ Wk, const ushort_t* __restrict__ Wv,
        const float* __restrict__ bk, const float* __restrict__ bv,
        ushort_t* __restrict__ outk, ushort_t* __restrict__ outv){
    __shared__ __align__(16) ushort_t wl[128*136];
    int tid = threadIdx.x;
    int lane = tid & 63, wave = tid >> 6;
    int m0 = blockIdx.x*128 + wave*32;
    int lr = lane & 15, hi4 = lane >> 4;
    int lk = hi4 * 8;
    const ushort_t* arow0 = A + (size_t)(m0 + lr)*128 + lk;
    const ushort_t* arow1 = arow0 + 16*128;
    short8 h0[4], h1[4];
    #pragma unroll
    for (int kc=0;kc<4;++kc){
        h0[kc] = *(const short8*)(arow0 + kc*32);
        h1[kc] = *(const short8*)(arow1 + kc*32);
    }
    #pragma unroll
    for (int i=0;i<8;++i){
        int elem = tid*8 + i*2048;
        int row = elem >> 7, k = elem & 127;
        *(short8*)&wl[row*136 + k] = *(const short8*)&Wk[elem];
    }
    __syncthreads();
    {
        f32x4 acc[2][8];
        #pragma unroll
        for (int t=0;t<2;++t)
            #pragma unroll
            for (int nt=0;nt<8;++nt) acc[t][nt] = (f32x4){0.f,0.f,0.f,0.f};
        #pragma unroll
        for (int kc=0; kc<4; ++kc){
            #pragma unroll
            for (int nt=0; nt<8; ++nt){
                short8 wf = *(const short8*)&wl[(nt*16 + lr)*136 + kc*32 + lk];
                acc[0][nt] = __builtin_amdgcn_mfma_f32_16x16x32_bf16(wf, h0[kc], acc[0][nt], 0, 0, 0);
                acc[1][nt] = __builtin_amdgcn_mfma_f32_16x16x32_bf16(wf, h1[kc], acc[1][nt], 0, 0, 0);
            }
        }
        #pragma unroll
        for (int nt=0; nt<8; ++nt){
            int n0 = nt*16 + hi4*4;
            float4 b4 = *(const float4*)&bk[n0];
            #pragma unroll
            for (int t=0; t<2; ++t){
                size_t m = (size_t)m0 + t*16 + lr;
                uint2 pk;
                pk.x = pk2bf(acc[t][nt][0]+b4.x, acc[t][nt][1]+b4.y);
                pk.y = pk2bf(acc[t][nt][2]+b4.z, acc[t][nt][3]+b4.w);
                *(uint2*)&outk[m*128 + n0] = pk;
            }
        }
    }
    __syncthreads();
    #pragma unroll
    for (int i=0;i<8;++i){
        int elem = tid*8 + i*2048;
        int row = elem >> 7, k = elem & 127;
        *(short8*)&wl[row*136 + k] = *(const short8*)&Wv[elem];
    }
    __syncthreads();
    {
        f32x4 acc[2][8];
        #pragma unroll
        for (int t=0;t<2;++t)
            #pragma unroll
            for (int nt=0;nt<8;++nt) acc[t][nt] = (f32x4){0.f,0.f,0.f,0.f};
        #pragma unroll
        for (int kc=0; kc<4; ++kc){
            #pragma unroll
            for (int nt=0; nt<8; ++nt){
                short8 wf = *(const short8*)&wl[(nt*16 + lr)*136 + kc*32 + lk];
                acc[0][nt] = __builtin_amdgcn_mfma_f32_16x16x32_bf16(wf, h0[kc], acc[0][nt], 0, 0, 0);
                acc[1][nt] = __builtin_amdgcn_mfma_f32_16x16x32_bf16(wf, h1[kc], acc[1][nt], 0, 0, 0);
            }
        }
        #pragma unroll
        for (int nt=0; nt<8; ++nt){
            int n0 = nt*16 + hi4*4;
            float4 b4 = *(const float4*)&bv[n0];
            #pragma unroll
            for (int t=0; t<2; ++t){
                size_t m = (size_t)m0 + t*16 + lr;
                uint2 pk;
                pk.x = pk2bf(acc[t][nt][0]+b4.x, acc[t][nt][1]+b4.y);
                pk.y = pk2bf(acc[t][nt][2]+b4.z, acc[t][nt][3]+b4.w);
                *(uint2*)&outv[m*128 + n0] = pk;
            }
        }
    }
}

// ---------------- GCN aggregate: 8 nodes/wave (8 lanes x 2 uint4), 4-deep loop + LN ----------
__global__ __launch_bounds__(256) void gcn_agg(ushort_t* __restrict__ hbf, const ushort_t* __restrict__ hwbf,
        const int* __restrict__ offs, const int2* __restrict__ ee,
        const float* __restrict__ dinv, const float* __restrict__ bias,
        const float* __restrict__ lnw, const float* __restrict__ lnb, int last){
    int wave = threadIdx.x >> 6;
    int lane = threadIdx.x & 63;
    int g = lane >> 3, sl = lane & 7;            // 8 nodes/wave, 8 lanes/node
    int node = blockIdx.x*32 + wave*8 + g;
    const uint4* hwu = (const uint4*)hwbf;       // row = 16 uint4
    uint4* hbu = (uint4*)hbf;
    int bi = sl*2;                                // lane's uint4 pair within the row
    uint4 sv0 = hwu[(size_t)node*16 + bi];
    uint4 sv1 = hwu[(size_t)node*16 + bi + 1];
    uint4 rv0 = make_uint4(0,0,0,0), rv1 = make_uint4(0,0,0,0);
    if (!last){
        rv0 = hbu[(size_t)node*16 + bi];
        rv1 = hbu[(size_t)node*16 + bi + 1];
    }
    float di = dinv[node];
    float sw = di*di;
    float a[16], b[16];
    #pragma unroll
    for (int j=0;j<16;++j){ a[j]=0.f; b[j]=0.f; }
    acc8(a, sw, sv0, 0); acc8(a, sw, sv1, 8);
    int e0 = offs[node], e1 = offs[node+1];
    int e = e0;
    for (; e + 4 <= e1; e += 4){
        int2 p0 = ee[e], p1 = ee[e+1], p2 = ee[e+2], p3 = ee[e+3];
        uint4 u00 = hwu[(size_t)p0.x*16 + bi], u01 = hwu[(size_t)p0.x*16 + bi + 1];
        uint4 u10 = hwu[(size_t)p1.x*16 + bi], u11 = hwu[(size_t)p1.x*16 + bi + 1];
        uint4 u20 = hwu[(size_t)p2.x*16 + bi], u21 = hwu[(size_t)p2.x*16 + bi + 1];
        uint4 u30 = hwu[(size_t)p3.x*16 + bi], u31 = hwu[(size_t)p3.x*16 + bi + 1];
        float w0 = __int_as_float(p0.y), w1 = __int_as_float(p1.y);
        float w2 = __int_as_float(p2.y), w3 = __int_as_float(p3.y);
        acc8(a, w0, u00, 0); acc8(a, w0, u01, 8);
        acc8(b, w1, u10, 0); acc8(b, w1, u11, 8);
        acc8(a, w2, u20, 0); acc8(a, w2, u21, 8);
        acc8(b, w3, u30, 0); acc8(b, w3, u31, 8);
    }
    if (e + 2 <= e1){
        int2 p0 = ee[e], p1 = ee[e+1];
        uint4 u00 = hwu[(size_t)p0.x*16 + bi], u01 = hwu[(size_t)p0.x*16 + bi + 1];
        uint4 u10 = hwu[(size_t)p1.x*16 + bi], u11 = hwu[(size_t)p1.x*16 + bi + 1];
        float w0 = __int_as_float(p0.y), w1 = __int_as_float(p1.y);
        acc8(a, w0, u00, 0); acc8(a, w0, u01, 8);
        acc8(b, w1, u10, 0); acc8(b, w1, u11, 8);
        e += 2;
    }
    if (e < e1){
        int2 p0 = ee[e];
        uint4 u00 = hwu[(size_t)p0.x*16 + bi], u01 = hwu[(size_t)p0.x*16 + bi + 1];
        float w0 = __int_as_float(p0.y);
        acc8(a, w0, u00, 0); acc8(a, w0, u01, 8);
    }
    #pragma unroll
    for (int j=0;j<16;++j) a[j] += b[j];
    // bias: lane covers dims sl*16 .. sl*16+15 = float4 indices sl*4 .. sl*4+3
    {
        const float4* b4p = (const float4*)bias;
        #pragma unroll
        for (int q=0;q<4;++q){
            float4 bb = b4p[sl*4 + q];
            a[q*4+0] += bb.x; a[q*4+1] += bb.y; a[q*4+2] += bb.z; a[q*4+3] += bb.w;
        }
    }
    // LN over 128 dims = 8 lanes x 16 dims (within group: xor 1,2,4)
    float s = 0.f;
    #pragma unroll
    for (int j=0;j<16;++j) s += a[j];
    s += __shfl_xor(s,1); s += __shfl_xor(s,2); s += __shfl_xor(s,4);
    float mean = s*(1.f/128.f);
    float var = 0.f;
    #pragma unroll
    for (int j=0;j<16;++j){ a[j] -= mean; var += a[j]*a[j]; }
    var += __shfl_xor(var,1); var += __shfl_xor(var,2); var += __shfl_xor(var,4);
    float rs = rsqrtf(var*(1.f/128.f) + 1e-5f);
    float y[16];
    {
        const float4* wp = (const float4*)lnw;
        const float4* lp = (const float4*)lnb;
        #pragma unroll
        for (int q=0;q<4;++q){
            float4 wv = wp[sl*4 + q], lv = lp[sl*4 + q];
            y[q*4+0] = a[q*4+0]*rs*wv.x + lv.x;
            y[q*4+1] = a[q*4+1]*rs*wv.y + lv.y;
            y[q*4+2] = a[q*4+2]*rs*wv.z + lv.z;
            y[q*4+3] = a[q*4+3]*rs*wv.w + lv.w;
        }
    }
    if (!last){
        y[0]  = fmaxf(y[0], 0.f) + bfu_lo(rv0.x);
        y[1]  = fmaxf(y[1], 0.f) + bfu_hi(rv0.x);
        y[2]  = fmaxf(y[2], 0.f) + bfu_lo(rv0.y);
        y[3]  = fmaxf(y[3], 0.f) + bfu_hi(rv0.y);
        y[4]  = fmaxf(y[4], 0.f) + bfu_lo(rv0.z);
        y[5]  = fmaxf(y[5], 0.f) + bfu_hi(rv0.z);
        y[6]  = fmaxf(y[6], 0.f) + bfu_lo(rv0.w);
        y[7]  = fmaxf(y[7], 0.f) + bfu_hi(rv0.w);
        y[8]  = fmaxf(y[8], 0.f) + bfu_lo(rv1.x);
        y[9]  = fmaxf(y[9], 0.f) + bfu_hi(rv1.x);
        y[10] = fmaxf(y[10],0.f) + bfu_lo(rv1.y);
        y[11] = fmaxf(y[11],0.f) + bfu_hi(rv1.y);
        y[12] = fmaxf(y[12],0.f) + bfu_lo(rv1.z);
        y[13] = fmaxf(y[13],0.f) + bfu_hi(rv1.z);
        y[14] = fmaxf(y[14],0.f) + bfu_lo(rv1.w);
        y[15] = fmaxf(y[15],0.f) + bfu_hi(rv1.w);
    }
    uint4 o0, o1;
    o0.x = pk2bf(y[0], y[1]);  o0.y = pk2bf(y[2], y[3]);
    o0.z = pk2bf(y[4], y[5]);  o0.w = pk2bf(y[6], y[7]);
    o1.x = pk2bf(y[8], y[9]);  o1.y = pk2bf(y[10],y[11]);
    o1.z = pk2bf(y[12],y[13]); o1.w = pk2bf(y[14],y[15]);
    hbu[(size_t)node*16 + bi]     = o0;
    hbu[(size_t)node*16 + bi + 1] = o1;
}

// ---------------- decoder MFMA GEMM: flexible K, NO via grid.y ----------------
// flags: 1=acc from out(fp32), 2=relu, 4=write outbf, 8=write out fp32, 16=acc from t12 bcast
__global__ __launch_bounds__(256) void dec_gemm(const ushort_t* __restrict__ A,
        const ushort_t* __restrict__ Wb, const float* __restrict__ bias,
        float* __restrict__ out, ushort_t* __restrict__ outbf,
        const float* __restrict__ tbc,
        int K, int NO, int flags){
    int lane = threadIdx.x & 63, wave = threadIdx.x >> 6;
    int m0 = blockIdx.x*64 + wave*16;
    int n0 = blockIdx.y*128;
    int lr = lane & 15, lk = (lane>>4)*8;
    f32x4 acc[8];
    #pragma unroll
    for (int nt=0; nt<8; ++nt) acc[nt] = (f32x4){0.f,0.f,0.f,0.f};
    for (int ko = 0; ko < K; ko += 128){
        short8 bfrag[4][8];
        #pragma unroll
        for (int nt=0; nt<8; ++nt)
            #pragma unroll
            for (int kc=0; kc<4; ++kc)
                bfrag[kc][nt] = *(const short8*)&Wb[(size_t)(n0 + nt*16 + lr)*K + ko + kc*32 + lk];
        const ushort_t* arow = A + (size_t)(m0 + lr)*K + ko + lk;
        #pragma unroll
        for (int kc=0; kc<4; ++kc){
            short8 a = *(const short8*)(arow + kc*32);
            #pragma unroll
            for (int nt=0; nt<8; ++nt)
                acc[nt] = __builtin_amdgcn_mfma_f32_16x16x32_bf16(a, bfrag[kc][nt], acc[nt], 0, 0, 0);
        }
    }
    int orow0 = m0 + (lane>>4)*4;
    #pragma unroll
    for (int nt=0; nt<8; ++nt){
        int col = n0 + nt*16 + lr;
        float bv = bias[col];
        #pragma unroll
        for (int r=0; r<4; ++r){
            int row = orow0 + r;
            size_t idx = (size_t)row*NO + col;
            float val = acc[nt][r] + bv;
            if (flags & 2) val = fmaxf(val, 0.f);
            if (flags & 1) val += out[idx];
            if (flags & 16) val += tbc[(row % 12)*128 + col];
            if (flags & 8) out[idx] = val;
            if (flags & 4) outbf[idx] = f2bf(val);
        }
    }
}

// ---------------- decoder small ops (multi-launch batch-invariant prefix) ----------------
__global__ __launch_bounds__(256) void ln_rows(const float* __restrict__ x, float* __restrict__ y,
        const float* __restrict__ w, const float* __restrict__ b){
    int r = blockIdx.x*4 + (threadIdx.x>>6);
    int lane = threadIdx.x & 63;
    const float2* x2 = (const float2*)(x + (size_t)r*128);
    float2 v = x2[lane];
    float s = v.x+v.y;
    for (int o=32;o>0;o>>=1) s += __shfl_xor(s,o);
    float mean = s*(1.f/128.f);
    float dx=v.x-mean, dy=v.y-mean;
    float var = dx*dx+dy*dy;
    for (int o=32;o>0;o>>=1) var += __shfl_xor(var,o);
    float rs = rsqrtf(var*(1.f/128.f) + 1e-5f);
    float2 w2=((const float2*)w)[lane], b2=((const float2*)b)[lane];
    ((float2*)(y + (size_t)r*128))[lane] = make_float2(dx*rs*w2.x+b2.x, dy*rs*w2.y+b2.y);
}

__global__ __launch_bounds__(256) void ln_rows_bf(const float* __restrict__ x, ushort_t* __restrict__ y,
        const float* __restrict__ w, const float* __restrict__ b){
    int r = blockIdx.x*4 + (threadIdx.x>>6);
    int lane = threadIdx.x & 63;
    const float2* x2 = (const float2*)(x + (size_t)r*128);
    float2 v = x2[lane];
    float s = v.x+v.y;
    for (int o=32;o>0;o>>=1) s += __shfl_xor(s,o);
    float mean = s*(1.f/128.f);
    float dx=v.x-mean, dy=v.y-mean;
    float var = dx*dx+dy*dy;
    for (int o=32;o>0;o>>=1) var += __shfl_xor(var,o);
    float rs = rsqrtf(var*(1.f/128.f) + 1e-5f);
    float2 w2=((const float2*)w)[lane], b2=((const float2*)b)[lane];
    float yx = dx*rs*w2.x+b2.x, yy = dy*rs*w2.y+b2.y;
    ((unsigned*)y)[(size_t)r*64 + lane] = pk2bf(yx, yy);
}

// naive fp32 gemm for 12-row prefix. flags: 1=acc from out, 2=relu; base!=null adds base[idx]
__global__ __launch_bounds__(256) void small_gemm(const float* __restrict__ x, const float* __restrict__ W,
        const float* __restrict__ bias, float* __restrict__ out, const float* __restrict__ base,
        int R, int K, int NO, int flags){
    int idx = blockIdx.x*256 + threadIdx.x;
    if (idx >= R*NO) return;
    int r = idx / NO, n = idx - r*NO;
    const float4* xr = (const float4*)(x + (size_t)r*K);
    const float4* wr = (const float4*)(W + (size_t)n*K);
    float a = bias ? bias[n] : 0.0f;
    int K4 = K>>2;
    for (int k=0;k<K4;++k){
        float4 xv = xr[k], wv = wr[k];
        a += xv.x*wv.x + xv.y*wv.y + xv.z*wv.z + xv.w*wv.w;
    }
    if (flags & 2) a = fmaxf(a, 0.f);
    if (flags & 1) a += out[idx];
    if (base) a += base[idx];
    out[idx] = a;
}

__global__ __launch_bounds__(64) void self_attn12(const float* __restrict__ qkv, float* __restrict__ out){
    int hh = blockIdx.x;
    int lane = threadIdx.x;
    __shared__ float q[12][32], k[12][32], v[12][32], sc[12][12];
    for (int idx = lane; idx < 12*32; idx += 64){
        int c = idx>>5, d = idx&31;
        size_t base = (size_t)c*384 + hh*32 + d;
        q[c][d] = qkv[base] * 0.17677669529663687f;
        k[c][d] = qkv[base+128];
        v[c][d] = qkv[base+256];
    }
    __syncthreads();
    for (int p = lane; p < 144; p += 64){
        int qi = p/12, ki = p%12;
        float a = 0;
        #pragma unroll
        for (int d=0; d<32; ++d) a += q[qi][d]*k[ki][d];
        sc[qi][ki] = a;
    }
    __syncthreads();
    if (lane < 12){
        float m = -1e30f;
        for (int j=0;j<12;++j) m = fmaxf(m, sc[lane][j]);
        float sum=0;
        for (int j=0;j<12;++j){ float e=__expf(sc[lane][j]-m); sc[lane][j]=e; sum+=e; }
        float inv=1.f/sum;
        for (int j=0;j<12;++j) sc[lane][j]*=inv;
    }
    __syncthreads();
    for (int p = lane; p < 384; p += 64){
        int c = p>>5, d = p&31;
        float a=0;
        #pragma unroll
        for (int j=0;j<12;++j) a += sc[c][j]*v[j][d];
        out[(size_t)c*128 + hh*32 + d] = a;
    }
}

// ---------------- flash cross-attention, k-split, MFMA; shared q12 ----------------
__global__ __launch_bounds__(512) void cross_attn_part(const float* __restrict__ q12,
        const ushort_t* __restrict__ K, const ushort_t* __restrict__ V,
        float* __restrict__ opart, float2* __restrict__ mlpart){
    __shared__ __align__(16) ushort_t qs[16*136];
    __shared__ __align__(16) unsigned char uni[128*136*2];
    __shared__ __align__(16) ushort_t pbf[4*16*136];
    __shared__ float2 ml[48];
    float* s32 = (float*)uni;
    ushort_t* vt = (ushort_t*)uni;

    int tid = threadIdx.x;
    int b = blockIdx.x / NSPLIT, sp = blockIdx.x % NSPLIT;
    int k0 = sp * CHUNK;
    int lane = tid & 63, w = tid >> 6;
    int lr = lane & 15, hi8 = (lane >> 4) * 8;

    const unsigned* Vu = (const unsigned*)V + ((size_t)b*1000 + k0)*64;
    unsigned vreg[16];
    #pragma unroll
    for (int j=0;j<15;++j) vreg[j] = Vu[tid + j*512];
    if (tid < 320) vreg[15] = Vu[tid + 7680];

    for (int i = tid; i < 16*128; i += 512){
        int r = i >> 7, c = i & 127;
        ushort_t v = 0;
        if (r < 12) v = f2bf(q12[r*128 + c] * 0.17677669529663687f);
        qs[r*136 + c] = v;
    }
    for (int i = tid; i < 4352; i += 512) ((unsigned*)pbf)[i] = 0;
    __syncthreads();

    {
        int krow = k0 + w*16 + lr; if (krow > k0 + 124) krow = k0 + 124;
        const ushort_t* Krow = K + ((size_t)b*1000 + krow)*128 + hi8;
        #pragma unroll
        for (int h=0; h<4; ++h){
            short8 kf = *(const short8*)(Krow + h*32);
            short8 qf = *(const short8*)&qs[lr*136 + h*32 + hi8];
            f32x4 d = __builtin_amdgcn_mfma_f32_16x16x32_bf16(qf, kf, (f32x4){0,0,0,0}, 0, 0, 0);
            int qbase = (lane>>4)*4;
            #pragma unroll
            for (int r=0; r<4; ++r){
                int qq = qbase + r;
                if (qq < 12) s32[(h*12+qq)*130 + w*16 + lr] = d[r];
            }
        }
    }
    __syncthreads();

    if (tid < 192){
        int hq = tid >> 2, sub = tid & 3;
        int h = hq / 12, qq = hq - h*12;
        float m = -1e30f;
        for (int kk = sub; kk < CHUNK; kk += 4) m = fmaxf(m, s32[hq*130 + kk]);
        m = fmaxf(m, __shfl_xor(m, 1));
        m = fmaxf(m, __shfl_xor(m, 2));
        float l = 0.f;
        for (int kk = sub; kk < CHUNK; kk += 4){
            float e = __expf(s32[hq*130 + kk] - m);
            l += e;
            pbf[(h*16+qq)*136 + kk] = f2bf(e);
        }
        l += __shfl_xor(l, 1);
        l += __shfl_xor(l, 2);
        if (sub == 0) ml[hq] = make_float2(m, l);
    }
    __syncthreads();

    #pragma unroll
    for (int j=0;j<15;++j){
        int i = tid + j*512;
        int kk = i >> 6, dp = (i & 63)*2;
        unsigned u = vreg[j];
        vt[dp*136 + kk]     = (ushort_t)(u & 0xFFFF);
        vt[(dp+1)*136 + kk] = (ushort_t)(u >> 16);
    }
    if (tid < 320){
        int i = tid + 7680;
        int kk = i >> 6, dp = (i & 63)*2;
        unsigned u = vreg[15];
        vt[dp*136 + kk]     = (ushort_t)(u & 0xFFFF);
        vt[(dp+1)*136 + kk] = (ushort_t)(u >> 16);
    }
    if (tid < 384){
        int dp = tid / 3, kk = 125 + tid % 3;
        vt[dp*136 + kk] = 0;
    }
    __syncthreads();

    {
        int h = w >> 1;
        f32x4 acc = (f32x4){0,0,0,0};
        #pragma unroll
        for (int kc=0; kc<4; ++kc){
            short8 pf = *(const short8*)&pbf[(h*16+lr)*136 + kc*32 + hi8];
            short8 vf = *(const short8*)&vt[(w*16+lr)*136 + kc*32 + hi8];
            acc = __builtin_amdgcn_mfma_f32_16x16x32_bf16(pf, vf, acc, 0, 0, 0);
        }
        int qbase = (lane>>4)*4;
        float* ob = opart + ((size_t)(b*NSPLIT+sp)*12)*128;
        #pragma unroll
        for (int r=0; r<4; ++r){
            int qq = qbase + r;
            if (qq < 12) ob[(size_t)qq*128 + w*16 + lr] = acc[r];
        }
    }
    if (tid < 48) mlpart[(size_t)(b*NSPLIT+sp)*48 + tid] = ml[tid];
}

__global__ __launch_bounds__(256) void cross_attn_comb(const float* __restrict__ opart,
        const float* __restrict__ mlpart, ushort_t* __restrict__ attbf){
    int b = blockIdx.x, tid = threadIdx.x;
    __shared__ float mls[NSPLIT*48*2];
    for (int i = tid; i < NSPLIT*48*2; i += 256) mls[i] = mlpart[(size_t)b*NSPLIT*96 + i];
    __syncthreads();
    for (int p = tid; p < 1536; p += 256){
        int qq = p >> 7, dp = p & 127, h = dp >> 5, hq = h*12 + qq;
        float M = -1e30f;
        #pragma unroll
        for (int sp=0; sp<NSPLIT; ++sp) M = fmaxf(M, mls[sp*96 + hq*2]);
        float L = 0.f, O = 0.f;
        #pragma unroll
        for (int sp=0; sp<NSPLIT; ++sp){
            float wgt = __expf(mls[sp*96 + hq*2] - M);
            L += wgt * mls[sp*96 + hq*2 + 1];
            O += wgt * opart[((size_t)(b*NSPLIT+sp)*12 + qq)*128 + dp];
        }
        attbf[((size_t)b*12 + qq)*128 + dp] = f2bf(O / L);
    }
}

__global__ __launch_bounds__(256) void final_out(const float* __restrict__ t,
        const float* __restrict__ lw, const float* __restrict__ lb,
        const float* __restrict__ ow, const float* __restrict__ ob, float* __restrict__ out){
    int r = blockIdx.x*4 + (threadIdx.x>>6);
    int lane = threadIdx.x & 63;
    const float2* x2 = (const float2*)(t + (size_t)r*128);
    float2 v = x2[lane];
    float s = v.x+v.y;
    for (int o=32;o>0;o>>=1) s += __shfl_xor(s,o);
    float mean = s*(1.f/128.f);
    float dx=v.x-mean, dy=v.y-mean;
    float var = dx*dx+dy*dy;
    for (int o=32;o>0;o>>=1) var += __shfl_xor(var,o);
    float rs = rsqrtf(var*(1.f/128.f)+1e-5f);
    float2 w2=((const float2*)lw)[lane], b2=((const float2*)lb)[lane];
    float2 o2=((const float2*)ow)[lane];
    float d = (dx*rs*w2.x+b2.x)*o2.x + (dy*rs*w2.y+b2.y)*o2.y;
    for (int o=32;o>0;o>>=1) d += __shfl_xor(d,o);
    if (lane==0) out[r] = d + ob[0];
}

extern "C" void kernel_launch(void* const* d_in, const int* in_sizes, int n_in,
                              void* d_out, int out_size, void* d_ws, size_t ws_size,
                              hipStream_t stream){
    (void)in_sizes; (void)n_in; (void)out_size; (void)ws_size;
    const float* x        = (const float*)d_in[0];
    const int*   eidx     = (const int*)d_in[1];
    const float* in_w     = (const float*)d_in[3];
    const float* in_b     = (const float*)d_in[4];
    const float* gcn_w    = (const float*)d_in[5];
    const float* gcn_b    = (const float*)d_in[6];
    const float* ln_w     = (const float*)d_in[7];
    const float* ln_b     = (const float*)d_in[8];
    const float* cq       = (const float*)d_in[9];
    const float* sa_qkv_w = (const float*)d_in[10];
    const float* sa_qkv_b = (const float*)d_in[11];
    const float* sa_out_w = (const float*)d_in[12];
    const float* sa_out_b = (const float*)d_in[13];
    const float* ca_qkv_w = (const float*)d_in[14];
    const float* ca_qkv_b = (const float*)d_in[15];
    const float* ca_out_w = (const float*)d_in[16];
    const float* ca_out_b = (const float*)d_in[17];
    const float* n1w=(const float*)d_in[18]; const float* n1b=(const float*)d_in[19];
    const float* n2w=(const float*)d_in[20]; const float* n2b=(const float*)d_in[21];
    const float* n3w=(const float*)d_in[22]; const float* n3b=(const float*)d_in[23];
    const float* ff1w=(const float*)d_in[24]; const float* ff1b=(const float*)d_in[25];
    const float* ff2w=(const float*)d_in[26]; const float* ff2b=(const float*)d_in[27];
    const float* opln_w=(const float*)d_in[28]; const float* opln_b=(const float*)d_in[29];
    const float* opw=(const float*)d_in[30]; const float* opb=(const float*)d_in[31];
    float* out = (float*)d_out;

    char* base = (char*)d_ws;
    size_t off = 0;
    auto alloc = [&](size_t bytes)->void*{
        void* r = base + off; off += (bytes + 255) & ~(size_t)255; return r;
    };
    ushort_t* hbf   = (ushort_t*)alloc((size_t)NNODES*DD*2);
    ushort_t* kbf   = (ushort_t*)alloc((size_t)NNODES*DD*2);  // also hwbf during GCN loop
    ushort_t* vbf   = (ushort_t*)alloc((size_t)NNODES*DD*2);
    ushort_t* Wb    = (ushort_t*)alloc((size_t)5*DD*DD*2);
    ushort_t* Wpad  = (ushort_t*)alloc((size_t)DD*32*2);
    ushort_t* Wdec  = (ushort_t*)alloc((size_t)147456*2);
    float*    dinv  = (float*)alloc((size_t)NNODES*4);
    int*      cnt   = (int*)  alloc((size_t)NNODES*4);
    int*      offs  = (int*)  alloc((size_t)(NNODES+1)*4);
    int*      bsum  = (int*)  alloc(512*4);
    int2*     ee    = (int2*) alloc((size_t)NEDGES*8);
    float*    t12   = (float*)alloc((size_t)12*DD*4);
    float*    tn12  = (float*)alloc((size_t)12*DD*4);
    float*    sq12  = (float*)alloc((size_t)12*384*4);
    float*    att12 = (float*)alloc((size_t)12*DD*4);
    float*    q12   = (float*)alloc((size_t)12*DD*4);
    float*    tfull = (float*)alloc((size_t)NROWS*DD*4);
    ushort_t* tnbf  = (ushort_t*)alloc((size_t)NROWS*DD*2);
    ushort_t* attbf = (ushort_t*)alloc((size_t)NROWS*DD*2);
    ushort_t* ffhbf = (ushort_t*)alloc((size_t)NROWS*512*2);
    float*    opart = (float*)alloc((size_t)BB*NSPLIT*12*128*4);
    float2*   mlprt = (float2*)alloc((size_t)BB*NSPLIT*48*8);
    ushort_t* hwbf  = kbf;

    const int* erow = eidx;
    const int* ecol = eidx + NEDGES;

    // CSR build (once, reused by all 3 GCN layers)
    hipMemsetAsync(cnt, 0, (size_t)NNODES*4, stream);
    count_edges<<<NEDGES/256, 256, 0, stream>>>(ecol, cnt);
    scan_a<<<NNODES/256, 256, 0, stream>>>(cnt, offs, bsum, dinv);
    scan_b<<<1, 512, 0, stream>>>(bsum, NNODES/256);
    scan_c<<<NNODES/256, 256, 0, stream>>>(offs, bsum);
    hipMemsetAsync(cnt, 0, (size_t)NNODES*4, stream);
    fill_csr<<<NEDGES/256, 256, 0, stream>>>(erow, ecol, offs, cnt, dinv, ee);

    conv_all<<<912, 256, 0, stream>>>(gcn_w, ca_qkv_w, in_w, ca_out_w, ff1w, ff2w, Wb, Wpad, Wdec);

    // node pipeline (residual lives in hbf as bf16)
    in_proj_mfma<<<NNODES/64, 256, 0, stream>>>(x, Wpad, in_b, hbf);
    for (int i=0;i<3;++i){
        gemm_mfma<<<NNODES/128, 256, 0, stream>>>(hbf, Wb + (size_t)i*DD*DD, nullptr, hwbf);
        gcn_agg<<<NNODES/32, 256, 0, stream>>>(hbf, hwbf, offs, ee, dinv,
                gcn_b + (size_t)i*DD, ln_w + (size_t)i*DD, ln_b + (size_t)i*DD, i==2);
    }
    // fused cross-attn K+V projections (A read once)
    gemm_mfma_kv<<<NNODES/128, 256, 0, stream>>>(hbf, Wb + (size_t)3*DD*DD, Wb + (size_t)4*DD*DD,
            ca_qkv_b + DD, ca_qkv_b + 2*DD, kbf, vbf);

    // ---- decoder: batch-invariant 12-row prefix (fp32, exact, multi-launch) ----
    ln_rows<<<3, 256, 0, stream>>>(cq, tn12, n1w, n1b);
    small_gemm<<<18, 256, 0, stream>>>(tn12, sa_qkv_w, sa_qkv_b, sq12, nullptr, 12, 128, 384, 0);
    self_attn12<<<4, 64, 0, stream>>>(sq12, att12);
    small_gemm<<<6, 256, 0, stream>>>(att12, sa_out_w, sa_out_b, t12, cq, 12, 128, 128, 0);
    ln_rows<<<3, 256, 0, stream>>>(t12, tn12, n2w, n2b);
    small_gemm<<<6, 256, 0, stream>>>(tn12, ca_qkv_w, ca_qkv_b, q12, nullptr, 12, 128, 128, 0);

    // ---- per-batch: cross-attention + FF (bf16 MFMA) ----
    cross_attn_part<<<BB*NSPLIT, 512, 0, stream>>>(q12, kbf, vbf, opart, mlprt);
    cross_attn_comb<<<BB, 256, 0, stream>>>(opart, (const float*)mlprt, attbf);
    dim3 g24_1(24,1), g24_4(24,4);
    dec_gemm<<<g24_1, 256, 0, stream>>>(attbf, Wdec, ca_out_b, tfull, nullptr, t12, 128, 128, 16|8);
    ln_rows_bf<<<NROWS/4, 256, 0, stream>>>(tfull, tnbf, n3w, n3b);
    dec_gemm<<<g24_4, 256, 0, stream>>>(tnbf, Wdec + 16384, ff1b, nullptr, ffhbf, nullptr, 128, 512, 2|4);
    dec_gemm<<<g24_1, 256, 0, stream>>>(ffhbf, Wdec + 81920, ff2b, tfull, nullptr, nullptr, 512, 128, 1|8);
    final_out<<<NROWS/4, 256, 0, stream>>>(tfull, opln_w, opln_b, opw, opb, out);
}

// Round 17
// 421.373 us; speedup vs baseline: 1.0247x; 1.0247x over previous
//
#include <hip/hip_runtime.h>
#include <hip/hip_bf16.h>

#define NNODES 128000
#define NEDGES 640000
#define BB 128
#define CC 12
#define DD 128
#define NROWS (BB*CC)   // 1536
#define NSPLIT 8
#define CHUNK 125

typedef __attribute__((ext_vector_type(8))) short short8;
typedef __attribute__((ext_vector_type(4))) float f32x4;
typedef unsigned short ushort_t;

__device__ __forceinline__ unsigned pk2bf(float lo, float hi){
    union { __hip_bfloat162 h; unsigned u; } v;
    v.h = __float22bfloat162_rn(make_float2(lo, hi));
    return v.u;
}
__device__ __forceinline__ ushort_t f2bf(float f){
    union { __hip_bfloat16 h; ushort_t u; } v;
    v.h = __float2bfloat16(f);
    return v.u;
}
__device__ __forceinline__ float bfu_lo(unsigned u){
    union { unsigned u; float f; } v; v.u = u << 16; return v.f;
}
__device__ __forceinline__ float bfu_hi(unsigned u){
    union { unsigned u; float f; } v; v.u = u & 0xFFFF0000u; return v.f;
}

// ---------------- CSR build ----------------
__global__ __launch_bounds__(256) void count_edges(const int* __restrict__ col, int* __restrict__ cnt){
    int e = blockIdx.x*256 + threadIdx.x;
    if (e < NEDGES) atomicAdd(&cnt[col[e]], 1);
}

// scan_a also emits dinv (reads cnt anyway)
__global__ __launch_bounds__(256) void scan_a(const int* __restrict__ cnt, int* __restrict__ offs,
        int* __restrict__ bsum, float* __restrict__ dinv){
    __shared__ int tmp[256];
    int tid = threadIdx.x;
    int g = blockIdx.x*256 + tid;
    int v = cnt[g];
    dinv[g] = rsqrtf((float)v + 1.0f);
    tmp[tid] = v;
    __syncthreads();
    for (int o=1;o<256;o<<=1){
        int a = (tid>=o)? tmp[tid-o] : 0;
        __syncthreads();
        tmp[tid] += a;
        __syncthreads();
    }
    offs[g] = tmp[tid] - v;
    if (tid==255) bsum[blockIdx.x] = tmp[255];
}

__global__ __launch_bounds__(512) void scan_b(int* __restrict__ bsum, int NB){
    __shared__ int tmp[512];
    int tid = threadIdx.x;
    int v = (tid<NB)? bsum[tid] : 0;
    tmp[tid] = v;
    __syncthreads();
    for (int o=1;o<512;o<<=1){
        int a = (tid>=o)? tmp[tid-o] : 0;
        __syncthreads();
        tmp[tid] += a;
        __syncthreads();
    }
    if (tid<NB) bsum[tid] = tmp[tid] - v;
}

__global__ __launch_bounds__(256) void scan_c(int* __restrict__ offs, const int* __restrict__ bsum){
    int g = blockIdx.x*256 + threadIdx.x;
    offs[g] += bsum[g>>8];
    if (g==0) offs[NNODES] = NEDGES;
}

__global__ __launch_bounds__(256) void fill_csr(const int* __restrict__ row, const int* __restrict__ col,
        const int* __restrict__ offs, int* __restrict__ cur, const float* __restrict__ dinv,
        int2* __restrict__ ee){
    int e = blockIdx.x*256 + threadIdx.x;
    if (e >= NEDGES) return;
    int c = col[e], r = row[e];
    int p = atomicAdd(&cur[c], 1);
    int idx = offs[c] + p;
    float w = dinv[r]*dinv[c];
    ee[idx] = make_int2(r, __float_as_int(w));
}

// ---------------- all weight conversions in one kernel ----------------
__global__ __launch_bounds__(256) void conv_all(const float* __restrict__ gcn_w,
        const float* __restrict__ ca_qkv_w, const float* __restrict__ in_w,
        const float* __restrict__ caout, const float* __restrict__ ff1, const float* __restrict__ ff2,
        ushort_t* __restrict__ Wb, ushort_t* __restrict__ Wpad, ushort_t* __restrict__ Wd){
    int i = blockIdx.x*256 + threadIdx.x;   // < 233472
    if (i < 81920){
        int slot = i >> 14, off = i & 16383;
        float v = (slot < 3) ? gcn_w[slot*16384 + off]
                             : ca_qkv_w[16384 + (slot-3)*16384 + off];
        Wb[i] = f2bf(v);
    } else if (i < 86016){
        int j = i - 81920;
        int n = j >> 5, k = j & 31;
        Wpad[j] = (k < 16) ? f2bf(in_w[n*16 + k]) : (ushort_t)0;
    } else {
        int j = i - 86016;   // < 147456
        float v;
        if (j < 16384) v = caout[j];
        else if (j < 81920) v = ff1[j - 16384];
        else v = ff2[j - 81920];
        Wd[j] = f2bf(v);
    }
}

// ---------------- input projection via MFMA (swapped operands, uint2 stores) ----------------
__global__ __launch_bounds__(256) void in_proj_mfma(const float* __restrict__ x,
        const ushort_t* __restrict__ Wpad, const float* __restrict__ bias,
        ushort_t* __restrict__ hbf){
    __shared__ __align__(16) ushort_t xs[64*40];
    int tid = threadIdx.x;
    int m0 = blockIdx.x*64;
    if (tid < 128){
        short8 z = {0,0,0,0,0,0,0,0};
        *(short8*)&xs[(tid>>1)*40 + 16 + (tid&1)*8] = z;
    }
    float4 xv = *(const float4*)(x + (size_t)m0*16 + tid*4);
    uint2 pk2;
    pk2.x = pk2bf(xv.x, xv.y);
    pk2.y = pk2bf(xv.z, xv.w);
    *(uint2*)&xs[(tid>>2)*40 + (tid&3)*4] = pk2;
    __syncthreads();
    int lane = tid & 63, w = tid >> 6;
    int lr = lane & 15, hi4 = lane >> 4, lk = hi4*8;
    short8 wf[8];
    #pragma unroll
    for (int nt=0; nt<8; ++nt)
        wf[nt] = *(const short8*)&Wpad[(nt*16 + lr)*32 + lk];
    short8 a = *(const short8*)&xs[(w*16 + lr)*40 + lk];
    f32x4 acc[8];
    #pragma unroll
    for (int nt=0; nt<8; ++nt)
        acc[nt] = __builtin_amdgcn_mfma_f32_16x16x32_bf16(wf[nt], a, (f32x4){0,0,0,0}, 0, 0, 0);
    size_t m = (size_t)m0 + w*16 + lr;
    #pragma unroll
    for (int nt=0; nt<8; ++nt){
        int n0 = nt*16 + hi4*4;
        float4 bv = *(const float4*)&bias[n0];
        uint2 pk;
        pk.x = pk2bf(acc[nt][0]+bv.x, acc[nt][1]+bv.y);
        pk.y = pk2bf(acc[nt][2]+bv.z, acc[nt][3]+bv.w);
        *(uint2*)&hbf[m*128 + n0] = pk;
    }
}

// ---------------- MFMA GEMM, swapped operands (D rows = n, cols = m) --------------
__global__ __launch_bounds__(256) void gemm_mfma(const ushort_t* __restrict__ A,
        const ushort_t* __restrict__ Wb, const float* __restrict__ bias, ushort_t* __restrict__ out){
    __shared__ __align__(16) ushort_t wl[128*136];
    int tid = threadIdx.x;
    #pragma unroll
    for (int i=0;i<8;++i){
        int elem = tid*8 + i*2048;
        int row = elem >> 7, k = elem & 127;
        *(short8*)&wl[row*136 + k] = *(const short8*)&Wb[elem];
    }
    __syncthreads();
    int lane = tid & 63, wave = tid >> 6;
    int m0 = blockIdx.x*128 + wave*32;
    int lr = lane & 15, hi4 = lane >> 4;
    int lk = hi4 * 8;
    f32x4 acc[2][8];
    #pragma unroll
    for (int t=0;t<2;++t)
        #pragma unroll
        for (int nt=0;nt<8;++nt) acc[t][nt] = (f32x4){0.f,0.f,0.f,0.f};
    const ushort_t* arow0 = A + (size_t)(m0 + lr)*128 + lk;
    const ushort_t* arow1 = arow0 + 16*128;
    #pragma unroll
    for (int kc=0; kc<4; ++kc){
        short8 h0 = *(const short8*)(arow0 + kc*32);
        short8 h1 = *(const short8*)(arow1 + kc*32);
        #pragma unroll
        for (int nt=0; nt<8; ++nt){
            short8 wf = *(const short8*)&wl[(nt*16 + lr)*136 + kc*32 + lk];
            acc[0][nt] = __builtin_amdgcn_mfma_f32_16x16x32_bf16(wf, h0, acc[0][nt], 0, 0, 0);
            acc[1][nt] = __builtin_amdgcn_mfma_f32_16x16x32_bf16(wf, h1, acc[1][nt], 0, 0, 0);
        }
    }
    #pragma unroll
    for (int nt=0; nt<8; ++nt){
        int n0 = nt*16 + hi4*4;
        float b0=0.f,b1=0.f,b2=0.f,b3=0.f;
        if (bias){
            float4 bv = *(const float4*)&bias[n0];
            b0=bv.x; b1=bv.y; b2=bv.z; b3=bv.w;
        }
        #pragma unroll
        for (int t=0; t<2; ++t){
            size_t m = (size_t)m0 + t*16 + lr;
            uint2 pk;
            pk.x = pk2bf(acc[t][nt][0]+b0, acc[t][nt][1]+b1);
            pk.y = pk2bf(acc[t][nt][2]+b2, acc[t][nt][3]+b3);
            *(uint2*)&out[m*128 + n0] = pk;
        }
    }
}

// ---------------- fused K+V GEMM: A loaded once to registers, W staged twice ----------
__global__ __launch_bounds__(256) void gemm_mfma_kv(const ushort_t* __restrict__ A,
        const ushort_t* __restrict__ Wk, const ushort_t* __restrict__ Wv,
        const float* __restrict__ bk, const float* __restrict__ bv,
        ushort_t* __restrict__ outk, ushort_t* __restrict__ outv){
    __shared__ __align__(16) ushort_t wl[128*136];
    int tid = threadIdx.x;
    int lane = tid & 63, wave = tid >> 6;
    int m0 = blockIdx.x*128 + wave*32;
    int lr = lane & 15, hi4 = lane >> 4;
    int lk = hi4 * 8;
    const ushort_t* arow0 = A + (size_t)(m0 + lr)*128 + lk;
    const ushort_t* arow1 = arow0 + 16*128;
    short8 h0[4], h1[4];
    #pragma unroll
    for (int kc=0;kc<4;++kc){
        h0[kc] = *(const short8*)(arow0 + kc*32);
        h1[kc] = *(const short8*)(arow1 + kc*32);
    }
    #pragma unroll
    for (int i=0;i<8;++i){
        int elem = tid*8 + i*2048;
        int row = elem >> 7, k = elem & 127;
        *(short8*)&wl[row*136 + k] = *(const short8*)&Wk[elem];
    }
    __syncthreads();
    {
        f32x4 acc[2][8];
        #pragma unroll
        for (int t=0;t<2;++t)
            #pragma unroll
            for (int nt=0;nt<8;++nt) acc[t][nt] = (f32x4){0.f,0.f,0.f,0.f};
        #pragma unroll
        for (int kc=0; kc<4; ++kc){
            #pragma unroll
            for (int nt=0; nt<8; ++nt){
                short8 wf = *(const short8*)&wl[(nt*16 + lr)*136 + kc*32 + lk];
                acc[0][nt] = __builtin_amdgcn_mfma_f32_16x16x32_bf16(wf, h0[kc], acc[0][nt], 0, 0, 0);
                acc[1][nt] = __builtin_amdgcn_mfma_f32_16x16x32_bf16(wf, h1[kc], acc[1][nt], 0, 0, 0);
            }
        }
        #pragma unroll
        for (int nt=0; nt<8; ++nt){
            int n0 = nt*16 + hi4*4;
            float4 b4 = *(const float4*)&bk[n0];
            #pragma unroll
            for (int t=0; t<2; ++t){
                size_t m = (size_t)m0 + t*16 + lr;
                uint2 pk;
                pk.x = pk2bf(acc[t][nt][0]+b4.x, acc[t][nt][1]+b4.y);
                pk.y = pk2bf(acc[t][nt][2]+b4.z, acc[t][nt][3]+b4.w);
                *(uint2*)&outk[m*128 + n0] = pk;
            }
        }
    }
    __syncthreads();
    #pragma unroll
    for (int i=0;i<8;++i){
        int elem = tid*8 + i*2048;
        int row = elem >> 7, k = elem & 127;
        *(short8*)&wl[row*136 + k] = *(const short8*)&Wv[elem];
    }
    __syncthreads();
    {
        f32x4 acc[2][8];
        #pragma unroll
        for (int t=0;t<2;++t)
            #pragma unroll
            for (int nt=0;nt<8;++nt) acc[t][nt] = (f32x4){0.f,0.f,0.f,0.f};
        #pragma unroll
        for (int kc=0; kc<4; ++kc){
            #pragma unroll
            for (int nt=0; nt<8; ++nt){
                short8 wf = *(const short8*)&wl[(nt*16 + lr)*136 + kc*32 + lk];
                acc[0][nt] = __builtin_amdgcn_mfma_f32_16x16x32_bf16(wf, h0[kc], acc[0][nt], 0, 0, 0);
                acc[1][nt] = __builtin_amdgcn_mfma_f32_16x16x32_bf16(wf, h1[kc], acc[1][nt], 0, 0, 0);
            }
        }
        #pragma unroll
        for (int nt=0; nt<8; ++nt){
            int n0 = nt*16 + hi4*4;
            float4 b4 = *(const float4*)&bv[n0];
            #pragma unroll
            for (int t=0; t<2; ++t){
                size_t m = (size_t)m0 + t*16 + lr;
                uint2 pk;
                pk.x = pk2bf(acc[t][nt][0]+b4.x, acc[t][nt][1]+b4.y);
                pk.y = pk2bf(acc[t][nt][2]+b4.z, acc[t][nt][3]+b4.w);
                *(uint2*)&outv[m*128 + n0] = pk;
            }
        }
    }
}

// ---------------- GCN aggregate: 4 nodes/wave (16 lanes x uint4), 4-deep loop + LN ----------
__global__ __launch_bounds__(256) void gcn_agg(ushort_t* __restrict__ hbf, const ushort_t* __restrict__ hwbf,
        const int* __restrict__ offs, const int2* __restrict__ ee,
        const float* __restrict__ dinv, const float* __restrict__ bias,
        const float* __restrict__ lnw, const float* __restrict__ lnb, int last){
    int wave = threadIdx.x >> 6;
    int lane = threadIdx.x & 63;
    int g = lane >> 4, sl = lane & 15;
    int node = blockIdx.x*16 + wave*4 + g;
    const uint4* hwu = (const uint4*)hwbf;
    uint4* hbu = (uint4*)hbf;
    uint4 sv = hwu[(size_t)node*16 + sl];
    uint4 rv = make_uint4(0,0,0,0);
    if (!last) rv = hbu[(size_t)node*16 + sl];
    float di = dinv[node];
    float sw = di*di;
    float a0 = sw*bfu_lo(sv.x), a1 = sw*bfu_hi(sv.x);
    float a2 = sw*bfu_lo(sv.y), a3 = sw*bfu_hi(sv.y);
    float a4 = sw*bfu_lo(sv.z), a5 = sw*bfu_hi(sv.z);
    float a6 = sw*bfu_lo(sv.w), a7 = sw*bfu_hi(sv.w);
    float b0=0,b1=0,b2=0,b3=0,b4=0,b5=0,b6=0,b7=0;
    int e0 = offs[node], e1 = offs[node+1];
    int e = e0;
    for (; e + 4 <= e1; e += 4){
        int2 p0 = ee[e], p1 = ee[e+1], p2 = ee[e+2], p3 = ee[e+3];
        uint4 u0 = hwu[(size_t)p0.x*16 + sl];
        uint4 u1 = hwu[(size_t)p1.x*16 + sl];
        uint4 u2 = hwu[(size_t)p2.x*16 + sl];
        uint4 u3 = hwu[(size_t)p3.x*16 + sl];
        float w0 = __int_as_float(p0.y), w1 = __int_as_float(p1.y);
        float w2 = __int_as_float(p2.y), w3 = __int_as_float(p3.y);
        a0 += w0*bfu_lo(u0.x); a1 += w0*bfu_hi(u0.x); a2 += w0*bfu_lo(u0.y); a3 += w0*bfu_hi(u0.y);
        a4 += w0*bfu_lo(u0.z); a5 += w0*bfu_hi(u0.z); a6 += w0*bfu_lo(u0.w); a7 += w0*bfu_hi(u0.w);
        b0 += w1*bfu_lo(u1.x); b1 += w1*bfu_hi(u1.x); b2 += w1*bfu_lo(u1.y); b3 += w1*bfu_hi(u1.y);
        b4 += w1*bfu_lo(u1.z); b5 += w1*bfu_hi(u1.z); b6 += w1*bfu_lo(u1.w); b7 += w1*bfu_hi(u1.w);
        a0 += w2*bfu_lo(u2.x); a1 += w2*bfu_hi(u2.x); a2 += w2*bfu_lo(u2.y); a3 += w2*bfu_hi(u2.y);
        a4 += w2*bfu_lo(u2.z); a5 += w2*bfu_hi(u2.z); a6 += w2*bfu_lo(u2.w); a7 += w2*bfu_hi(u2.w);
        b0 += w3*bfu_lo(u3.x); b1 += w3*bfu_hi(u3.x); b2 += w3*bfu_lo(u3.y); b3 += w3*bfu_hi(u3.y);
        b4 += w3*bfu_lo(u3.z); b5 += w3*bfu_hi(u3.z); b6 += w3*bfu_lo(u3.w); b7 += w3*bfu_hi(u3.w);
    }
    if (e + 2 <= e1){
        int2 p0 = ee[e], p1 = ee[e+1];
        uint4 u0 = hwu[(size_t)p0.x*16 + sl];
        uint4 u1 = hwu[(size_t)p1.x*16 + sl];
        float w0 = __int_as_float(p0.y), w1 = __int_as_float(p1.y);
        a0 += w0*bfu_lo(u0.x); a1 += w0*bfu_hi(u0.x); a2 += w0*bfu_lo(u0.y); a3 += w0*bfu_hi(u0.y);
        a4 += w0*bfu_lo(u0.z); a5 += w0*bfu_hi(u0.z); a6 += w0*bfu_lo(u0.w); a7 += w0*bfu_hi(u0.w);
        b0 += w1*bfu_lo(u1.x); b1 += w1*bfu_hi(u1.x); b2 += w1*bfu_lo(u1.y); b3 += w1*bfu_hi(u1.y);
        b4 += w1*bfu_lo(u1.z); b5 += w1*bfu_hi(u1.z); b6 += w1*bfu_lo(u1.w); b7 += w1*bfu_hi(u1.w);
        e += 2;
    }
    if (e < e1){
        int2 p0 = ee[e];
        uint4 u0 = hwu[(size_t)p0.x*16 + sl];
        float w0 = __int_as_float(p0.y);
        a0 += w0*bfu_lo(u0.x); a1 += w0*bfu_hi(u0.x); a2 += w0*bfu_lo(u0.y); a3 += w0*bfu_hi(u0.y);
        a4 += w0*bfu_lo(u0.z); a5 += w0*bfu_hi(u0.z); a6 += w0*bfu_lo(u0.w); a7 += w0*bfu_hi(u0.w);
    }
    a0 += b0; a1 += b1; a2 += b2; a3 += b3;
    a4 += b4; a5 += b5; a6 += b6; a7 += b7;
    {
        const float4* b4p = (const float4*)bias;
        float4 bb0 = b4p[sl*2], bb1 = b4p[sl*2+1];
        a0 += bb0.x; a1 += bb0.y; a2 += bb0.z; a3 += bb0.w;
        a4 += bb1.x; a5 += bb1.y; a6 += bb1.z; a7 += bb1.w;
    }
    float s = ((a0+a1)+(a2+a3))+((a4+a5)+(a6+a7));
    s += __shfl_xor(s,1); s += __shfl_xor(s,2); s += __shfl_xor(s,4); s += __shfl_xor(s,8);
    float mean = s*(1.f/128.f);
    a0 -= mean; a1 -= mean; a2 -= mean; a3 -= mean;
    a4 -= mean; a5 -= mean; a6 -= mean; a7 -= mean;
    float var = ((a0*a0+a1*a1)+(a2*a2+a3*a3))+((a4*a4+a5*a5)+(a6*a6+a7*a7));
    var += __shfl_xor(var,1); var += __shfl_xor(var,2); var += __shfl_xor(var,4); var += __shfl_xor(var,8);
    float rs = rsqrtf(var*(1.f/128.f) + 1e-5f);
    float4 w0v = ((const float4*)lnw)[sl*2], w1v = ((const float4*)lnw)[sl*2+1];
    float4 l0v = ((const float4*)lnb)[sl*2], l1v = ((const float4*)lnb)[sl*2+1];
    float y0 = a0*rs*w0v.x + l0v.x;
    float y1 = a1*rs*w0v.y + l0v.y;
    float y2 = a2*rs*w0v.z + l0v.z;
    float y3 = a3*rs*w0v.w + l0v.w;
    float y4 = a4*rs*w1v.x + l1v.x;
    float y5 = a5*rs*w1v.y + l1v.y;
    float y6 = a6*rs*w1v.z + l1v.z;
    float y7 = a7*rs*w1v.w + l1v.w;
    if (!last){
        y0 = fmaxf(y0,0.f) + bfu_lo(rv.x);
        y1 = fmaxf(y1,0.f) + bfu_hi(rv.x);
        y2 = fmaxf(y2,0.f) + bfu_lo(rv.y);
        y3 = fmaxf(y3,0.f) + bfu_hi(rv.y);
        y4 = fmaxf(y4,0.f) + bfu_lo(rv.z);
        y5 = fmaxf(y5,0.f) + bfu_hi(rv.z);
        y6 = fmaxf(y6,0.f) + bfu_lo(rv.w);
        y7 = fmaxf(y7,0.f) + bfu_hi(rv.w);
    }
    uint4 pk;
    pk.x = pk2bf(y0, y1);
    pk.y = pk2bf(y2, y3);
    pk.z = pk2bf(y4, y5);
    pk.w = pk2bf(y6, y7);
    hbu[(size_t)node*16 + sl] = pk;
}

// ---------------- decoder MFMA GEMM: flexible K, NO via grid.y ----------------
// flags: 1=acc from out(fp32), 2=relu, 4=write outbf, 8=write out fp32, 16=acc from t12 bcast
__global__ __launch_bounds__(256) void dec_gemm(const ushort_t* __restrict__ A,
        const ushort_t* __restrict__ Wb, const float* __restrict__ bias,
        float* __restrict__ out, ushort_t* __restrict__ outbf,
        const float* __restrict__ tbc,
        int K, int NO, int flags){
    int lane = threadIdx.x & 63, wave = threadIdx.x >> 6;
    int m0 = blockIdx.x*64 + wave*16;
    int n0 = blockIdx.y*128;
    int lr = lane & 15, lk = (lane>>4)*8;
    f32x4 acc[8];
    #pragma unroll
    for (int nt=0; nt<8; ++nt) acc[nt] = (f32x4){0.f,0.f,0.f,0.f};
    for (int ko = 0; ko < K; ko += 128){
        short8 bfrag[4][8];
        #pragma unroll
        for (int nt=0; nt<8; ++nt)
            #pragma unroll
            for (int kc=0; kc<4; ++kc)
                bfrag[kc][nt] = *(const short8*)&Wb[(size_t)(n0 + nt*16 + lr)*K + ko + kc*32 + lk];
        const ushort_t* arow = A + (size_t)(m0 + lr)*K + ko + lk;
        #pragma unroll
        for (int kc=0; kc<4; ++kc){
            short8 a = *(const short8*)(arow + kc*32);
            #pragma unroll
            for (int nt=0; nt<8; ++nt)
                acc[nt] = __builtin_amdgcn_mfma_f32_16x16x32_bf16(a, bfrag[kc][nt], acc[nt], 0, 0, 0);
        }
    }
    int orow0 = m0 + (lane>>4)*4;
    #pragma unroll
    for (int nt=0; nt<8; ++nt){
        int col = n0 + nt*16 + lr;
        float bv = bias[col];
        #pragma unroll
        for (int r=0; r<4; ++r){
            int row = orow0 + r;
            size_t idx = (size_t)row*NO + col;
            float val = acc[nt][r] + bv;
            if (flags & 2) val = fmaxf(val, 0.f);
            if (flags & 1) val += out[idx];
            if (flags & 16) val += tbc[(row % 12)*128 + col];
            if (flags & 8) out[idx] = val;
            if (flags & 4) outbf[idx] = f2bf(val);
        }
    }
}

// ---------------- decoder small ops (multi-launch batch-invariant prefix) ----------------
__global__ __launch_bounds__(256) void ln_rows(const float* __restrict__ x, float* __restrict__ y,
        const float* __restrict__ w, const float* __restrict__ b){
    int r = blockIdx.x*4 + (threadIdx.x>>6);
    int lane = threadIdx.x & 63;
    const float2* x2 = (const float2*)(x + (size_t)r*128);
    float2 v = x2[lane];
    float s = v.x+v.y;
    for (int o=32;o>0;o>>=1) s += __shfl_xor(s,o);
    float mean = s*(1.f/128.f);
    float dx=v.x-mean, dy=v.y-mean;
    float var = dx*dx+dy*dy;
    for (int o=32;o>0;o>>=1) var += __shfl_xor(var,o);
    float rs = rsqrtf(var*(1.f/128.f) + 1e-5f);
    float2 w2=((const float2*)w)[lane], b2=((const float2*)b)[lane];
    ((float2*)(y + (size_t)r*128))[lane] = make_float2(dx*rs*w2.x+b2.x, dy*rs*w2.y+b2.y);
}

__global__ __launch_bounds__(256) void ln_rows_bf(const float* __restrict__ x, ushort_t* __restrict__ y,
        const float* __restrict__ w, const float* __restrict__ b){
    int r = blockIdx.x*4 + (threadIdx.x>>6);
    int lane = threadIdx.x & 63;
    const float2* x2 = (const float2*)(x + (size_t)r*128);
    float2 v = x2[lane];
    float s = v.x+v.y;
    for (int o=32;o>0;o>>=1) s += __shfl_xor(s,o);
    float mean = s*(1.f/128.f);
    float dx=v.x-mean, dy=v.y-mean;
    float var = dx*dx+dy*dy;
    for (int o=32;o>0;o>>=1) var += __shfl_xor(var,o);
    float rs = rsqrtf(var*(1.f/128.f) + 1e-5f);
    float2 w2=((const float2*)w)[lane], b2=((const float2*)b)[lane];
    float yx = dx*rs*w2.x+b2.x, yy = dy*rs*w2.y+b2.y;
    ((unsigned*)y)[(size_t)r*64 + lane] = pk2bf(yx, yy);
}

// naive fp32 gemm for 12-row prefix. flags: 1=acc from out, 2=relu; base!=null adds base[idx]
__global__ __launch_bounds__(256) void small_gemm(const float* __restrict__ x, const float* __restrict__ W,
        const float* __restrict__ bias, float* __restrict__ out, const float* __restrict__ base,
        int R, int K, int NO, int flags){
    int idx = blockIdx.x*256 + threadIdx.x;
    if (idx >= R*NO) return;
    int r = idx / NO, n = idx - r*NO;
    const float4* xr = (const float4*)(x + (size_t)r*K);
    const float4* wr = (const float4*)(W + (size_t)n*K);
    float a = bias ? bias[n] : 0.0f;
    int K4 = K>>2;
    for (int k=0;k<K4;++k){
        float4 xv = xr[k], wv = wr[k];
        a += xv.x*wv.x + xv.y*wv.y + xv.z*wv.z + xv.w*wv.w;
    }
    if (flags & 2) a = fmaxf(a, 0.f);
    if (flags & 1) a += out[idx];
    if (base) a += base[idx];
    out[idx] = a;
}

__global__ __launch_bounds__(64) void self_attn12(const float* __restrict__ qkv, float* __restrict__ out){
    int hh = blockIdx.x;
    int lane = threadIdx.x;
    __shared__ float q[12][32], k[12][32], v[12][32], sc[12][12];
    for (int idx = lane; idx < 12*32; idx += 64){
        int c = idx>>5, d = idx&31;
        size_t base = (size_t)c*384 + hh*32 + d;
        q[c][d] = qkv[base] * 0.17677669529663687f;
        k[c][d] = qkv[base+128];
        v[c][d] = qkv[base+256];
    }
    __syncthreads();
    for (int p = lane; p < 144; p += 64){
        int qi = p/12, ki = p%12;
        float a = 0;
        #pragma unroll
        for (int d=0; d<32; ++d) a += q[qi][d]*k[ki][d];
        sc[qi][ki] = a;
    }
    __syncthreads();
    if (lane < 12){
        float m = -1e30f;
        for (int j=0;j<12;++j) m = fmaxf(m, sc[lane][j]);
        float sum=0;
        for (int j=0;j<12;++j){ float e=__expf(sc[lane][j]-m); sc[lane][j]=e; sum+=e; }
        float inv=1.f/sum;
        for (int j=0;j<12;++j) sc[lane][j]*=inv;
    }
    __syncthreads();
    for (int p = lane; p < 384; p += 64){
        int c = p>>5, d = p&31;
        float a=0;
        #pragma unroll
        for (int j=0;j<12;++j) a += sc[c][j]*v[j][d];
        out[(size_t)c*128 + hh*32 + d] = a;
    }
}

// ---------------- flash cross-attention, k-split, MFMA; shared q12 ----------------
__global__ __launch_bounds__(512) void cross_attn_part(const float* __restrict__ q12,
        const ushort_t* __restrict__ K, const ushort_t* __restrict__ V,
        float* __restrict__ opart, float2* __restrict__ mlpart){
    __shared__ __align__(16) ushort_t qs[16*136];
    __shared__ __align__(16) unsigned char uni[128*136*2];
    __shared__ __align__(16) ushort_t pbf[4*16*136];
    __shared__ float2 ml[48];
    float* s32 = (float*)uni;
    ushort_t* vt = (ushort_t*)uni;

    int tid = threadIdx.x;
    int b = blockIdx.x / NSPLIT, sp = blockIdx.x % NSPLIT;
    int k0 = sp * CHUNK;
    int lane = tid & 63, w = tid >> 6;
    int lr = lane & 15, hi8 = (lane >> 4) * 8;

    const unsigned* Vu = (const unsigned*)V + ((size_t)b*1000 + k0)*64;
    unsigned vreg[16];
    #pragma unroll
    for (int j=0;j<15;++j) vreg[j] = Vu[tid + j*512];
    if (tid < 320) vreg[15] = Vu[tid + 7680];

    for (int i = tid; i < 16*128; i += 512){
        int r = i >> 7, c = i & 127;
        ushort_t v = 0;
        if (r < 12) v = f2bf(q12[r*128 + c] * 0.17677669529663687f);
        qs[r*136 + c] = v;
    }
    for (int i = tid; i < 4352; i += 512) ((unsigned*)pbf)[i] = 0;
    __syncthreads();

    {
        int krow = k0 + w*16 + lr; if (krow > k0 + 124) krow = k0 + 124;
        const ushort_t* Krow = K + ((size_t)b*1000 + krow)*128 + hi8;
        #pragma unroll
        for (int h=0; h<4; ++h){
            short8 kf = *(const short8*)(Krow + h*32);
            short8 qf = *(const short8*)&qs[lr*136 + h*32 + hi8];
            f32x4 d = __builtin_amdgcn_mfma_f32_16x16x32_bf16(qf, kf, (f32x4){0,0,0,0}, 0, 0, 0);
            int qbase = (lane>>4)*4;
            #pragma unroll
            for (int r=0; r<4; ++r){
                int qq = qbase + r;
                if (qq < 12) s32[(h*12+qq)*130 + w*16 + lr] = d[r];
            }
        }
    }
    __syncthreads();

    if (tid < 192){
        int hq = tid >> 2, sub = tid & 3;
        int h = hq / 12, qq = hq - h*12;
        float m = -1e30f;
        for (int kk = sub; kk < CHUNK; kk += 4) m = fmaxf(m, s32[hq*130 + kk]);
        m = fmaxf(m, __shfl_xor(m, 1));
        m = fmaxf(m, __shfl_xor(m, 2));
        float l = 0.f;
        for (int kk = sub; kk < CHUNK; kk += 4){
            float e = __expf(s32[hq*130 + kk] - m);
            l += e;
            pbf[(h*16+qq)*136 + kk] = f2bf(e);
        }
        l += __shfl_xor(l, 1);
        l += __shfl_xor(l, 2);
        if (sub == 0) ml[hq] = make_float2(m, l);
    }
    __syncthreads();

    #pragma unroll
    for (int j=0;j<15;++j){
        int i = tid + j*512;
        int kk = i >> 6, dp = (i & 63)*2;
        unsigned u = vreg[j];
        vt[dp*136 + kk]     = (ushort_t)(u & 0xFFFF);
        vt[(dp+1)*136 + kk] = (ushort_t)(u >> 16);
    }
    if (tid < 320){
        int i = tid + 7680;
        int kk = i >> 6, dp = (i & 63)*2;
        unsigned u = vreg[15];
        vt[dp*136 + kk]     = (ushort_t)(u & 0xFFFF);
        vt[(dp+1)*136 + kk] = (ushort_t)(u >> 16);
    }
    if (tid < 384){
        int dp = tid / 3, kk = 125 + tid % 3;
        vt[dp*136 + kk] = 0;
    }
    __syncthreads();

    {
        int h = w >> 1;
        f32x4 acc = (f32x4){0,0,0,0};
        #pragma unroll
        for (int kc=0; kc<4; ++kc){
            short8 pf = *(const short8*)&pbf[(h*16+lr)*136 + kc*32 + hi8];
            short8 vf = *(const short8*)&vt[(w*16+lr)*136 + kc*32 + hi8];
            acc = __builtin_amdgcn_mfma_f32_16x16x32_bf16(pf, vf, acc, 0, 0, 0);
        }
        int qbase = (lane>>4)*4;
        float* ob = opart + ((size_t)(b*NSPLIT+sp)*12)*128;
        #pragma unroll
        for (int r=0; r<4; ++r){
            int qq = qbase + r;
            if (qq < 12) ob[(size_t)qq*128 + w*16 + lr] = acc[r];
        }
    }
    if (tid < 48) mlpart[(size_t)(b*NSPLIT+sp)*48 + tid] = ml[tid];
}

__global__ __launch_bounds__(256) void cross_attn_comb(const float* __restrict__ opart,
        const float* __restrict__ mlpart, ushort_t* __restrict__ attbf){
    int b = blockIdx.x, tid = threadIdx.x;
    __shared__ float mls[NSPLIT*48*2];
    for (int i = tid; i < NSPLIT*48*2; i += 256) mls[i] = mlpart[(size_t)b*NSPLIT*96 + i];
    __syncthreads();
    for (int p = tid; p < 1536; p += 256){
        int qq = p >> 7, dp = p & 127, h = dp >> 5, hq = h*12 + qq;
        float M = -1e30f;
        #pragma unroll
        for (int sp=0; sp<NSPLIT; ++sp) M = fmaxf(M, mls[sp*96 + hq*2]);
        float L = 0.f, O = 0.f;
        #pragma unroll
        for (int sp=0; sp<NSPLIT; ++sp){
            float wgt = __expf(mls[sp*96 + hq*2] - M);
            L += wgt * mls[sp*96 + hq*2 + 1];
            O += wgt * opart[((size_t)(b*NSPLIT+sp)*12 + qq)*128 + dp];
        }
        attbf[((size_t)b*12 + qq)*128 + dp] = f2bf(O / L);
    }
}

__global__ __launch_bounds__(256) void final_out(const float* __restrict__ t,
        const float* __restrict__ lw, const float* __restrict__ lb,
        const float* __restrict__ ow, const float* __restrict__ ob, float* __restrict__ out){
    int r = blockIdx.x*4 + (threadIdx.x>>6);
    int lane = threadIdx.x & 63;
    const float2* x2 = (const float2*)(t + (size_t)r*128);
    float2 v = x2[lane];
    float s = v.x+v.y;
    for (int o=32;o>0;o>>=1) s += __shfl_xor(s,o);
    float mean = s*(1.f/128.f);
    float dx=v.x-mean, dy=v.y-mean;
    float var = dx*dx+dy*dy;
    for (int o=32;o>0;o>>=1) var += __shfl_xor(var,o);
    float rs = rsqrtf(var*(1.f/128.f)+1e-5f);
    float2 w2=((const float2*)lw)[lane], b2=((const float2*)lb)[lane];
    float2 o2=((const float2*)ow)[lane];
    float d = (dx*rs*w2.x+b2.x)*o2.x + (dy*rs*w2.y+b2.y)*o2.y;
    for (int o=32;o>0;o>>=1) d += __shfl_xor(d,o);
    if (lane==0) out[r] = d + ob[0];
}

extern "C" void kernel_launch(void* const* d_in, const int* in_sizes, int n_in,
                              void* d_out, int out_size, void* d_ws, size_t ws_size,
                              hipStream_t stream){
    (void)in_sizes; (void)n_in; (void)out_size; (void)ws_size;
    const float* x        = (const float*)d_in[0];
    const int*   eidx     = (const int*)d_in[1];
    const float* in_w     = (const float*)d_in[3];
    const float* in_b     = (const float*)d_in[4];
    const float* gcn_w    = (const float*)d_in[5];
    const float* gcn_b    = (const float*)d_in[6];
    const float* ln_w     = (const float*)d_in[7];
    const float* ln_b     = (const float*)d_in[8];
    const float* cq       = (const float*)d_in[9];
    const float* sa_qkv_w = (const float*)d_in[10];
    const float* sa_qkv_b = (const float*)d_in[11];
    const float* sa_out_w = (const float*)d_in[12];
    const float* sa_out_b = (const float*)d_in[13];
    const float* ca_qkv_w = (const float*)d_in[14];
    const float* ca_qkv_b = (const float*)d_in[15];
    const float* ca_out_w = (const float*)d_in[16];
    const float* ca_out_b = (const float*)d_in[17];
    const float* n1w=(const float*)d_in[18]; const float* n1b=(const float*)d_in[19];
    const float* n2w=(const float*)d_in[20]; const float* n2b=(const float*)d_in[21];
    const float* n3w=(const float*)d_in[22]; const float* n3b=(const float*)d_in[23];
    const float* ff1w=(const float*)d_in[24]; const float* ff1b=(const float*)d_in[25];
    const float* ff2w=(const float*)d_in[26]; const float* ff2b=(const float*)d_in[27];
    const float* opln_w=(const float*)d_in[28]; const float* opln_b=(const float*)d_in[29];
    const float* opw=(const float*)d_in[30]; const float* opb=(const float*)d_in[31];
    float* out = (float*)d_out;

    char* base = (char*)d_ws;
    size_t off = 0;
    auto alloc = [&](size_t bytes)->void*{
        void* r = base + off; off += (bytes + 255) & ~(size_t)255; return r;
    };
    ushort_t* hbf   = (ushort_t*)alloc((size_t)NNODES*DD*2);
    ushort_t* kbf   = (ushort_t*)alloc((size_t)NNODES*DD*2);  // also hwbf during GCN loop
    ushort_t* vbf   = (ushort_t*)alloc((size_t)NNODES*DD*2);
    ushort_t* Wb    = (ushort_t*)alloc((size_t)5*DD*DD*2);
    ushort_t* Wpad  = (ushort_t*)alloc((size_t)DD*32*2);
    ushort_t* Wdec  = (ushort_t*)alloc((size_t)147456*2);
    float*    dinv  = (float*)alloc((size_t)NNODES*4);
    int*      cnt   = (int*)  alloc((size_t)NNODES*4);
    int*      offs  = (int*)  alloc((size_t)(NNODES+1)*4);
    int*      bsum  = (int*)  alloc(512*4);
    int2*     ee    = (int2*) alloc((size_t)NEDGES*8);
    float*    t12   = (float*)alloc((size_t)12*DD*4);
    float*    tn12  = (float*)alloc((size_t)12*DD*4);
    float*    sq12  = (float*)alloc((size_t)12*384*4);
    float*    att12 = (float*)alloc((size_t)12*DD*4);
    float*    q12   = (float*)alloc((size_t)12*DD*4);
    float*    tfull = (float*)alloc((size_t)NROWS*DD*4);
    ushort_t* tnbf  = (ushort_t*)alloc((size_t)NROWS*DD*2);
    ushort_t* attbf = (ushort_t*)alloc((size_t)NROWS*DD*2);
    ushort_t* ffhbf = (ushort_t*)alloc((size_t)NROWS*512*2);
    float*    opart = (float*)alloc((size_t)BB*NSPLIT*12*128*4);
    float2*   mlprt = (float2*)alloc((size_t)BB*NSPLIT*48*8);
    ushort_t* hwbf  = kbf;

    const int* erow = eidx;
    const int* ecol = eidx + NEDGES;

    // CSR build (once, reused by all 3 GCN layers)
    hipMemsetAsync(cnt, 0, (size_t)NNODES*4, stream);
    count_edges<<<NEDGES/256, 256, 0, stream>>>(ecol, cnt);
    scan_a<<<NNODES/256, 256, 0, stream>>>(cnt, offs, bsum, dinv);
    scan_b<<<1, 512, 0, stream>>>(bsum, NNODES/256);
    scan_c<<<NNODES/256, 256, 0, stream>>>(offs, bsum);
    hipMemsetAsync(cnt, 0, (size_t)NNODES*4, stream);
    fill_csr<<<NEDGES/256, 256, 0, stream>>>(erow, ecol, offs, cnt, dinv, ee);

    conv_all<<<912, 256, 0, stream>>>(gcn_w, ca_qkv_w, in_w, ca_out_w, ff1w, ff2w, Wb, Wpad, Wdec);

    // node pipeline (residual lives in hbf as bf16)
    in_proj_mfma<<<NNODES/64, 256, 0, stream>>>(x, Wpad, in_b, hbf);
    for (int i=0;i<3;++i){
        gemm_mfma<<<NNODES/128, 256, 0, stream>>>(hbf, Wb + (size_t)i*DD*DD, nullptr, hwbf);
        gcn_agg<<<NNODES/16, 256, 0, stream>>>(hbf, hwbf, offs, ee, dinv,
                gcn_b + (size_t)i*DD, ln_w + (size_t)i*DD, ln_b + (size_t)i*DD, i==2);
    }
    // fused cross-attn K+V projections (A read once)
    gemm_mfma_kv<<<NNODES/128, 256, 0, stream>>>(hbf, Wb + (size_t)3*DD*DD, Wb + (size_t)4*DD*DD,
            ca_qkv_b + DD, ca_qkv_b + 2*DD, kbf, vbf);

    // ---- decoder: batch-invariant 12-row prefix (fp32, exact, multi-launch) ----
    ln_rows<<<3, 256, 0, stream>>>(cq, tn12, n1w, n1b);
    small_gemm<<<18, 256, 0, stream>>>(tn12, sa_qkv_w, sa_qkv_b, sq12, nullptr, 12, 128, 384, 0);
    self_attn12<<<4, 64, 0, stream>>>(sq12, att12);
    small_gemm<<<6, 256, 0, stream>>>(att12, sa_out_w, sa_out_b, t12, cq, 12, 128, 128, 0);
    ln_rows<<<3, 256, 0, stream>>>(t12, tn12, n2w, n2b);
    small_gemm<<<6, 256, 0, stream>>>(tn12, ca_qkv_w, ca_qkv_b, q12, nullptr, 12, 128, 128, 0);

    // ---- per-batch: cross-attention + FF (bf16 MFMA) ----
    cross_attn_part<<<BB*NSPLIT, 512, 0, stream>>>(q12, kbf, vbf, opart, mlprt);
    cross_attn_comb<<<BB, 256, 0, stream>>>(opart, (const float*)mlprt, attbf);
    dim3 g24_1(24,1), g24_4(24,4);
    dec_gemm<<<g24_1, 256, 0, stream>>>(attbf, Wdec, ca_out_b, tfull, nullptr, t12, 128, 128, 16|8);
    ln_rows_bf<<<NROWS/4, 256, 0, stream>>>(tfull, tnbf, n3w, n3b);
    dec_gemm<<<g24_4, 256, 0, stream>>>(tnbf, Wdec + 16384, ff1b, nullptr, ffhbf, nullptr, 128, 512, 2|4);
    dec_gemm<<<g24_1, 256, 0, stream>>>(ffhbf, Wdec + 81920, ff2b, tfull, nullptr, nullptr, 512, 128, 1|8);
    final_out<<<NROWS/4, 256, 0, stream>>>(tfull, opln_w, opln_b, opw, opb, out);
}

// Round 18
// 413.881 us; speedup vs baseline: 1.0432x; 1.0181x over previous
//
#include <hip/hip_runtime.h>
#include <hip/hip_bf16.h>

#define NNODES 128000
#define NEDGES 640000
#define BB 128
#define CC 12
#define DD 128
#define NROWS (BB*CC)   // 1536
#define NSPLIT 8
#define CHUNK 125

typedef __attribute__((ext_vector_type(8))) short short8;
typedef __attribute__((ext_vector_type(4))) float f32x4;
typedef unsigned short ushort_t;

__device__ __forceinline__ unsigned pk2bf(float lo, float hi){
    union { __hip_bfloat162 h; unsigned u; } v;
    v.h = __float22bfloat162_rn(make_float2(lo, hi));
    return v.u;
}
__device__ __forceinline__ ushort_t f2bf(float f){
    union { __hip_bfloat16 h; ushort_t u; } v;
    v.h = __float2bfloat16(f);
    return v.u;
}
__device__ __forceinline__ float bfu_lo(unsigned u){
    union { unsigned u; float f; } v; v.u = u << 16; return v.f;
}
__device__ __forceinline__ float bfu_hi(unsigned u){
    union { unsigned u; float f; } v; v.u = u & 0xFFFF0000u; return v.f;
}

// ---------------- CSR build ----------------
__global__ __launch_bounds__(256) void count_edges(const int* __restrict__ col, int* __restrict__ cnt){
    int e = blockIdx.x*256 + threadIdx.x;
    if (e < NEDGES) atomicAdd(&cnt[col[e]], 1);
}

// scan_a also emits dinv (reads cnt anyway)
__global__ __launch_bounds__(256) void scan_a(const int* __restrict__ cnt, int* __restrict__ offs,
        int* __restrict__ bsum, float* __restrict__ dinv){
    __shared__ int tmp[256];
    int tid = threadIdx.x;
    int g = blockIdx.x*256 + tid;
    int v = cnt[g];
    dinv[g] = rsqrtf((float)v + 1.0f);
    tmp[tid] = v;
    __syncthreads();
    for (int o=1;o<256;o<<=1){
        int a = (tid>=o)? tmp[tid-o] : 0;
        __syncthreads();
        tmp[tid] += a;
        __syncthreads();
    }
    offs[g] = tmp[tid] - v;
    if (tid==255) bsum[blockIdx.x] = tmp[255];
}

__global__ __launch_bounds__(512) void scan_b(int* __restrict__ bsum, int NB){
    __shared__ int tmp[512];
    int tid = threadIdx.x;
    int v = (tid<NB)? bsum[tid] : 0;
    tmp[tid] = v;
    __syncthreads();
    for (int o=1;o<512;o<<=1){
        int a = (tid>=o)? tmp[tid-o] : 0;
        __syncthreads();
        tmp[tid] += a;
        __syncthreads();
    }
    if (tid<NB) bsum[tid] = tmp[tid] - v;
}

__global__ __launch_bounds__(256) void scan_c(int* __restrict__ offs, const int* __restrict__ bsum){
    int g = blockIdx.x*256 + threadIdx.x;
    offs[g] += bsum[g>>8];
    if (g==0) offs[NNODES] = NEDGES;
}

__global__ __launch_bounds__(256) void fill_csr(const int* __restrict__ row, const int* __restrict__ col,
        const int* __restrict__ offs, int* __restrict__ cur, const float* __restrict__ dinv,
        int2* __restrict__ ee){
    int e = blockIdx.x*256 + threadIdx.x;
    if (e >= NEDGES) return;
    int c = col[e], r = row[e];
    int p = atomicAdd(&cur[c], 1);
    int idx = offs[c] + p;
    float w = dinv[r]*dinv[c];
    ee[idx] = make_int2(r, __float_as_int(w));
}

// ---------------- all weight conversions in one kernel ----------------
__global__ __launch_bounds__(256) void conv_all(const float* __restrict__ gcn_w,
        const float* __restrict__ ca_qkv_w, const float* __restrict__ in_w,
        const float* __restrict__ caout, const float* __restrict__ ff1, const float* __restrict__ ff2,
        ushort_t* __restrict__ Wb, ushort_t* __restrict__ Wpad, ushort_t* __restrict__ Wd){
    int i = blockIdx.x*256 + threadIdx.x;   // < 233472
    if (i < 81920){
        int slot = i >> 14, off = i & 16383;
        float v = (slot < 3) ? gcn_w[slot*16384 + off]
                             : ca_qkv_w[16384 + (slot-3)*16384 + off];
        Wb[i] = f2bf(v);
    } else if (i < 86016){
        int j = i - 81920;
        int n = j >> 5, k = j & 31;
        Wpad[j] = (k < 16) ? f2bf(in_w[n*16 + k]) : (ushort_t)0;
    } else {
        int j = i - 86016;   // < 147456
        float v;
        if (j < 16384) v = caout[j];
        else if (j < 81920) v = ff1[j - 16384];
        else v = ff2[j - 81920];
        Wd[j] = f2bf(v);
    }
}

// ---------------- input projection via MFMA (swapped operands, uint2 stores) ----------------
__global__ __launch_bounds__(256) void in_proj_mfma(const float* __restrict__ x,
        const ushort_t* __restrict__ Wpad, const float* __restrict__ bias,
        ushort_t* __restrict__ hbf){
    __shared__ __align__(16) ushort_t xs[64*40];
    int tid = threadIdx.x;
    int m0 = blockIdx.x*64;
    if (tid < 128){
        short8 z = {0,0,0,0,0,0,0,0};
        *(short8*)&xs[(tid>>1)*40 + 16 + (tid&1)*8] = z;
    }
    float4 xv = *(const float4*)(x + (size_t)m0*16 + tid*4);
    uint2 pk2;
    pk2.x = pk2bf(xv.x, xv.y);
    pk2.y = pk2bf(xv.z, xv.w);
    *(uint2*)&xs[(tid>>2)*40 + (tid&3)*4] = pk2;
    __syncthreads();
    int lane = tid & 63, w = tid >> 6;
    int lr = lane & 15, hi4 = lane >> 4, lk = hi4*8;
    short8 wf[8];
    #pragma unroll
    for (int nt=0; nt<8; ++nt)
        wf[nt] = *(const short8*)&Wpad[(nt*16 + lr)*32 + lk];
    short8 a = *(const short8*)&xs[(w*16 + lr)*40 + lk];
    f32x4 acc[8];
    #pragma unroll
    for (int nt=0; nt<8; ++nt)
        acc[nt] = __builtin_amdgcn_mfma_f32_16x16x32_bf16(wf[nt], a, (f32x4){0,0,0,0}, 0, 0, 0);
    size_t m = (size_t)m0 + w*16 + lr;
    #pragma unroll
    for (int nt=0; nt<8; ++nt){
        int n0 = nt*16 + hi4*4;
        float4 bv = *(const float4*)&bias[n0];
        uint2 pk;
        pk.x = pk2bf(acc[nt][0]+bv.x, acc[nt][1]+bv.y);
        pk.y = pk2bf(acc[nt][2]+bv.z, acc[nt][3]+bv.w);
        *(uint2*)&hbf[m*128 + n0] = pk;
    }
}

// ---------------- MFMA GEMM v2: 16 rows/wave, 64-row blocks, half-W staging ----------------
// grid = NNODES/64 = 2000 blocks. LDS = 64x132 ushorts (~17 KB). acc 32 + A-frags 16 VGPR.
__global__ __launch_bounds__(256) void gemm_mfma(const ushort_t* __restrict__ A,
        const ushort_t* __restrict__ Wb, const float* __restrict__ bias, ushort_t* __restrict__ out){
    __shared__ __align__(16) ushort_t wl[64*132];
    int tid = threadIdx.x;
    int lane = tid & 63, wave = tid >> 6;
    int m0 = blockIdx.x*64 + wave*16;
    int lr = lane & 15, hi4 = lane >> 4;
    int lk = hi4 * 8;
    // A rows loaded once (issued before staging; HBM latency hides under it)
    const ushort_t* arow = A + (size_t)(m0 + lr)*128 + lk;
    short8 h[4];
    #pragma unroll
    for (int kc=0;kc<4;++kc) h[kc] = *(const short8*)(arow + kc*32);
    f32x4 acc[8];
    #pragma unroll
    for (int j=0;j<8;++j) acc[j] = (f32x4){0.f,0.f,0.f,0.f};
    #pragma unroll
    for (int ph=0; ph<2; ++ph){
        if (ph) __syncthreads();   // WAR: all waves done with previous half
        #pragma unroll
        for (int i=0;i<4;++i){
            int e = tid*8 + i*2048;           // 0..8191
            int row = e >> 7, k = e & 127;
            *(short8*)&wl[row*132 + k] = *(const short8*)&Wb[(ph*64 + row)*128 + k];
        }
        __syncthreads();
        #pragma unroll
        for (int kc=0; kc<4; ++kc){
            #pragma unroll
            for (int nt=0; nt<4; ++nt){
                short8 wf = *(const short8*)&wl[(nt*16 + lr)*132 + kc*32 + lk];
                acc[ph*4+nt] = __builtin_amdgcn_mfma_f32_16x16x32_bf16(wf, h[kc], acc[ph*4+nt], 0, 0, 0);
            }
        }
    }
    size_t m = (size_t)m0 + lr;
    #pragma unroll
    for (int j=0; j<8; ++j){
        int n0 = j*16 + hi4*4;
        float b0=0.f,b1=0.f,b2=0.f,b3=0.f;
        if (bias){
            float4 bv = *(const float4*)&bias[n0];
            b0=bv.x; b1=bv.y; b2=bv.z; b3=bv.w;
        }
        uint2 pk;
        pk.x = pk2bf(acc[j][0]+b0, acc[j][1]+b1);
        pk.y = pk2bf(acc[j][2]+b2, acc[j][3]+b3);
        *(uint2*)&out[m*128 + n0] = pk;
    }
}

// ---------------- fused K+V GEMM v2: 16 rows/wave, half-W staging, acc reused K->V ----------
__global__ __launch_bounds__(256) void gemm_mfma_kv(const ushort_t* __restrict__ A,
        const ushort_t* __restrict__ Wk, const ushort_t* __restrict__ Wv,
        const float* __restrict__ bk, const float* __restrict__ bv,
        ushort_t* __restrict__ outk, ushort_t* __restrict__ outv){
    __shared__ __align__(16) ushort_t wl[64*132];
    int tid = threadIdx.x;
    int lane = tid & 63, wave = tid >> 6;
    int m0 = blockIdx.x*64 + wave*16;
    int lr = lane & 15, hi4 = lane >> 4;
    int lk = hi4 * 8;
    const ushort_t* arow = A + (size_t)(m0 + lr)*128 + lk;
    short8 h[4];
    #pragma unroll
    for (int kc=0;kc<4;++kc) h[kc] = *(const short8*)(arow + kc*32);
    size_t m = (size_t)m0 + lr;
    f32x4 acc[8];
    // ---- K ----
    #pragma unroll
    for (int j=0;j<8;++j) acc[j] = (f32x4){0.f,0.f,0.f,0.f};
    #pragma unroll
    for (int ph=0; ph<2; ++ph){
        if (ph) __syncthreads();
        #pragma unroll
        for (int i=0;i<4;++i){
            int e = tid*8 + i*2048;
            int row = e >> 7, k = e & 127;
            *(short8*)&wl[row*132 + k] = *(const short8*)&Wk[(ph*64 + row)*128 + k];
        }
        __syncthreads();
        #pragma unroll
        for (int kc=0; kc<4; ++kc){
            #pragma unroll
            for (int nt=0; nt<4; ++nt){
                short8 wf = *(const short8*)&wl[(nt*16 + lr)*132 + kc*32 + lk];
                acc[ph*4+nt] = __builtin_amdgcn_mfma_f32_16x16x32_bf16(wf, h[kc], acc[ph*4+nt], 0, 0, 0);
            }
        }
    }
    #pragma unroll
    for (int j=0; j<8; ++j){
        int n0 = j*16 + hi4*4;
        float4 bv4 = *(const float4*)&bk[n0];
        uint2 pk;
        pk.x = pk2bf(acc[j][0]+bv4.x, acc[j][1]+bv4.y);
        pk.y = pk2bf(acc[j][2]+bv4.z, acc[j][3]+bv4.w);
        *(uint2*)&outk[m*128 + n0] = pk;
    }
    // ---- V ----
    #pragma unroll
    for (int j=0;j<8;++j) acc[j] = (f32x4){0.f,0.f,0.f,0.f};
    #pragma unroll
    for (int ph=0; ph<2; ++ph){
        __syncthreads();   // WAR vs previous compute (K ph1 or V ph0)
        #pragma unroll
        for (int i=0;i<4;++i){
            int e = tid*8 + i*2048;
            int row = e >> 7, k = e & 127;
            *(short8*)&wl[row*132 + k] = *(const short8*)&Wv[(ph*64 + row)*128 + k];
        }
        __syncthreads();
        #pragma unroll
        for (int kc=0; kc<4; ++kc){
            #pragma unroll
            for (int nt=0; nt<4; ++nt){
                short8 wf = *(const short8*)&wl[(nt*16 + lr)*132 + kc*32 + lk];
                acc[ph*4+nt] = __builtin_amdgcn_mfma_f32_16x16x32_bf16(wf, h[kc], acc[ph*4+nt], 0, 0, 0);
            }
        }
    }
    #pragma unroll
    for (int j=0; j<8; ++j){
        int n0 = j*16 + hi4*4;
        float4 bv4 = *(const float4*)&bv[n0];
        uint2 pk;
        pk.x = pk2bf(acc[j][0]+bv4.x, acc[j][1]+bv4.y);
        pk.y = pk2bf(acc[j][2]+bv4.z, acc[j][3]+bv4.w);
        *(uint2*)&outv[m*128 + n0] = pk;
    }
}

// ---------------- GCN aggregate: 4 nodes/wave (16 lanes x uint4), 4-deep loop + LN ----------
__global__ __launch_bounds__(256) void gcn_agg(ushort_t* __restrict__ hbf, const ushort_t* __restrict__ hwbf,
        const int* __restrict__ offs, const int2* __restrict__ ee,
        const float* __restrict__ dinv, const float* __restrict__ bias,
        const float* __restrict__ lnw, const float* __restrict__ lnb, int last){
    int wave = threadIdx.x >> 6;
    int lane = threadIdx.x & 63;
    int g = lane >> 4, sl = lane & 15;
    int node = blockIdx.x*16 + wave*4 + g;
    const uint4* hwu = (const uint4*)hwbf;
    uint4* hbu = (uint4*)hbf;
    uint4 sv = hwu[(size_t)node*16 + sl];
    uint4 rv = make_uint4(0,0,0,0);
    if (!last) rv = hbu[(size_t)node*16 + sl];
    float di = dinv[node];
    float sw = di*di;
    float a0 = sw*bfu_lo(sv.x), a1 = sw*bfu_hi(sv.x);
    float a2 = sw*bfu_lo(sv.y), a3 = sw*bfu_hi(sv.y);
    float a4 = sw*bfu_lo(sv.z), a5 = sw*bfu_hi(sv.z);
    float a6 = sw*bfu_lo(sv.w), a7 = sw*bfu_hi(sv.w);
    float b0=0,b1=0,b2=0,b3=0,b4=0,b5=0,b6=0,b7=0;
    int e0 = offs[node], e1 = offs[node+1];
    int e = e0;
    for (; e + 4 <= e1; e += 4){
        int2 p0 = ee[e], p1 = ee[e+1], p2 = ee[e+2], p3 = ee[e+3];
        uint4 u0 = hwu[(size_t)p0.x*16 + sl];
        uint4 u1 = hwu[(size_t)p1.x*16 + sl];
        uint4 u2 = hwu[(size_t)p2.x*16 + sl];
        uint4 u3 = hwu[(size_t)p3.x*16 + sl];
        float w0 = __int_as_float(p0.y), w1 = __int_as_float(p1.y);
        float w2 = __int_as_float(p2.y), w3 = __int_as_float(p3.y);
        a0 += w0*bfu_lo(u0.x); a1 += w0*bfu_hi(u0.x); a2 += w0*bfu_lo(u0.y); a3 += w0*bfu_hi(u0.y);
        a4 += w0*bfu_lo(u0.z); a5 += w0*bfu_hi(u0.z); a6 += w0*bfu_lo(u0.w); a7 += w0*bfu_hi(u0.w);
        b0 += w1*bfu_lo(u1.x); b1 += w1*bfu_hi(u1.x); b2 += w1*bfu_lo(u1.y); b3 += w1*bfu_hi(u1.y);
        b4 += w1*bfu_lo(u1.z); b5 += w1*bfu_hi(u1.z); b6 += w1*bfu_lo(u1.w); b7 += w1*bfu_hi(u1.w);
        a0 += w2*bfu_lo(u2.x); a1 += w2*bfu_hi(u2.x); a2 += w2*bfu_lo(u2.y); a3 += w2*bfu_hi(u2.y);
        a4 += w2*bfu_lo(u2.z); a5 += w2*bfu_hi(u2.z); a6 += w2*bfu_lo(u2.w); a7 += w2*bfu_hi(u2.w);
        b0 += w3*bfu_lo(u3.x); b1 += w3*bfu_hi(u3.x); b2 += w3*bfu_lo(u3.y); b3 += w3*bfu_hi(u3.y);
        b4 += w3*bfu_lo(u3.z); b5 += w3*bfu_hi(u3.z); b6 += w3*bfu_lo(u3.w); b7 += w3*bfu_hi(u3.w);
    }
    if (e + 2 <= e1){
        int2 p0 = ee[e], p1 = ee[e+1];
        uint4 u0 = hwu[(size_t)p0.x*16 + sl];
        uint4 u1 = hwu[(size_t)p1.x*16 + sl];
        float w0 = __int_as_float(p0.y), w1 = __int_as_float(p1.y);
        a0 += w0*bfu_lo(u0.x); a1 += w0*bfu_hi(u0.x); a2 += w0*bfu_lo(u0.y); a3 += w0*bfu_hi(u0.y);
        a4 += w0*bfu_lo(u0.z); a5 += w0*bfu_hi(u0.z); a6 += w0*bfu_lo(u0.w); a7 += w0*bfu_hi(u0.w);
        b0 += w1*bfu_lo(u1.x); b1 += w1*bfu_hi(u1.x); b2 += w1*bfu_lo(u1.y); b3 += w1*bfu_hi(u1.y);
        b4 += w1*bfu_lo(u1.z); b5 += w1*bfu_hi(u1.z); b6 += w1*bfu_lo(u1.w); b7 += w1*bfu_hi(u1.w);
        e += 2;
    }
    if (e < e1){
        int2 p0 = ee[e];
        uint4 u0 = hwu[(size_t)p0.x*16 + sl];
        float w0 = __int_as_float(p0.y);
        a0 += w0*bfu_lo(u0.x); a1 += w0*bfu_hi(u0.x); a2 += w0*bfu_lo(u0.y); a3 += w0*bfu_hi(u0.y);
        a4 += w0*bfu_lo(u0.z); a5 += w0*bfu_hi(u0.z); a6 += w0*bfu_lo(u0.w); a7 += w0*bfu_hi(u0.w);
    }
    a0 += b0; a1 += b1; a2 += b2; a3 += b3;
    a4 += b4; a5 += b5; a6 += b6; a7 += b7;
    {
        const float4* b4p = (const float4*)bias;
        float4 bb0 = b4p[sl*2], bb1 = b4p[sl*2+1];
        a0 += bb0.x; a1 += bb0.y; a2 += bb0.z; a3 += bb0.w;
        a4 += bb1.x; a5 += bb1.y; a6 += bb1.z; a7 += bb1.w;
    }
    float s = ((a0+a1)+(a2+a3))+((a4+a5)+(a6+a7));
    s += __shfl_xor(s,1); s += __shfl_xor(s,2); s += __shfl_xor(s,4); s += __shfl_xor(s,8);
    float mean = s*(1.f/128.f);
    a0 -= mean; a1 -= mean; a2 -= mean; a3 -= mean;
    a4 -= mean; a5 -= mean; a6 -= mean; a7 -= mean;
    float var = ((a0*a0+a1*a1)+(a2*a2+a3*a3))+((a4*a4+a5*a5)+(a6*a6+a7*a7));
    var += __shfl_xor(var,1); var += __shfl_xor(var,2); var += __shfl_xor(var,4); var += __shfl_xor(var,8);
    float rs = rsqrtf(var*(1.f/128.f) + 1e-5f);
    float4 w0v = ((const float4*)lnw)[sl*2], w1v = ((const float4*)lnw)[sl*2+1];
    float4 l0v = ((const float4*)lnb)[sl*2], l1v = ((const float4*)lnb)[sl*2+1];
    float y0 = a0*rs*w0v.x + l0v.x;
    float y1 = a1*rs*w0v.y + l0v.y;
    float y2 = a2*rs*w0v.z + l0v.z;
    float y3 = a3*rs*w0v.w + l0v.w;
    float y4 = a4*rs*w1v.x + l1v.x;
    float y5 = a5*rs*w1v.y + l1v.y;
    float y6 = a6*rs*w1v.z + l1v.z;
    float y7 = a7*rs*w1v.w + l1v.w;
    if (!last){
        y0 = fmaxf(y0,0.f) + bfu_lo(rv.x);
        y1 = fmaxf(y1,0.f) + bfu_hi(rv.x);
        y2 = fmaxf(y2,0.f) + bfu_lo(rv.y);
        y3 = fmaxf(y3,0.f) + bfu_hi(rv.y);
        y4 = fmaxf(y4,0.f) + bfu_lo(rv.z);
        y5 = fmaxf(y5,0.f) + bfu_hi(rv.z);
        y6 = fmaxf(y6,0.f) + bfu_lo(rv.w);
        y7 = fmaxf(y7,0.f) + bfu_hi(rv.w);
    }
    uint4 pk;
    pk.x = pk2bf(y0, y1);
    pk.y = pk2bf(y2, y3);
    pk.z = pk2bf(y4, y5);
    pk.w = pk2bf(y6, y7);
    hbu[(size_t)node*16 + sl] = pk;
}

// ---------------- decoder MFMA GEMM: flexible K, NO via grid.y ----------------
// flags: 1=acc from out(fp32), 2=relu, 4=write outbf, 8=write out fp32, 16=acc from t12 bcast
__global__ __launch_bounds__(256) void dec_gemm(const ushort_t* __restrict__ A,
        const ushort_t* __restrict__ Wb, const float* __restrict__ bias,
        float* __restrict__ out, ushort_t* __restrict__ outbf,
        const float* __restrict__ tbc,
        int K, int NO, int flags){
    int lane = threadIdx.x & 63, wave = threadIdx.x >> 6;
    int m0 = blockIdx.x*64 + wave*16;
    int n0 = blockIdx.y*128;
    int lr = lane & 15, lk = (lane>>4)*8;
    f32x4 acc[8];
    #pragma unroll
    for (int nt=0; nt<8; ++nt) acc[nt] = (f32x4){0.f,0.f,0.f,0.f};
    for (int ko = 0; ko < K; ko += 128){
        short8 bfrag[4][8];
        #pragma unroll
        for (int nt=0; nt<8; ++nt)
            #pragma unroll
            for (int kc=0; kc<4; ++kc)
                bfrag[kc][nt] = *(const short8*)&Wb[(size_t)(n0 + nt*16 + lr)*K + ko + kc*32 + lk];
        const ushort_t* arow = A + (size_t)(m0 + lr)*K + ko + lk;
        #pragma unroll
        for (int kc=0; kc<4; ++kc){
            short8 a = *(const short8*)(arow + kc*32);
            #pragma unroll
            for (int nt=0; nt<8; ++nt)
                acc[nt] = __builtin_amdgcn_mfma_f32_16x16x32_bf16(a, bfrag[kc][nt], acc[nt], 0, 0, 0);
        }
    }
    int orow0 = m0 + (lane>>4)*4;
    #pragma unroll
    for (int nt=0; nt<8; ++nt){
        int col = n0 + nt*16 + lr;
        float bv = bias[col];
        #pragma unroll
        for (int r=0; r<4; ++r){
            int row = orow0 + r;
            size_t idx = (size_t)row*NO + col;
            float val = acc[nt][r] + bv;
            if (flags & 2) val = fmaxf(val, 0.f);
            if (flags & 1) val += out[idx];
            if (flags & 16) val += tbc[(row % 12)*128 + col];
            if (flags & 8) out[idx] = val;
            if (flags & 4) outbf[idx] = f2bf(val);
        }
    }
}

// ---------------- decoder small ops (multi-launch batch-invariant prefix) ----------------
__global__ __launch_bounds__(256) void ln_rows(const float* __restrict__ x, float* __restrict__ y,
        const float* __restrict__ w, const float* __restrict__ b){
    int r = blockIdx.x*4 + (threadIdx.x>>6);
    int lane = threadIdx.x & 63;
    const float2* x2 = (const float2*)(x + (size_t)r*128);
    float2 v = x2[lane];
    float s = v.x+v.y;
    for (int o=32;o>0;o>>=1) s += __shfl_xor(s,o);
    float mean = s*(1.f/128.f);
    float dx=v.x-mean, dy=v.y-mean;
    float var = dx*dx+dy*dy;
    for (int o=32;o>0;o>>=1) var += __shfl_xor(var,o);
    float rs = rsqrtf(var*(1.f/128.f) + 1e-5f);
    float2 w2=((const float2*)w)[lane], b2=((const float2*)b)[lane];
    ((float2*)(y + (size_t)r*128))[lane] = make_float2(dx*rs*w2.x+b2.x, dy*rs*w2.y+b2.y);
}

__global__ __launch_bounds__(256) void ln_rows_bf(const float* __restrict__ x, ushort_t* __restrict__ y,
        const float* __restrict__ w, const float* __restrict__ b){
    int r = blockIdx.x*4 + (threadIdx.x>>6);
    int lane = threadIdx.x & 63;
    const float2* x2 = (const float2*)(x + (size_t)r*128);
    float2 v = x2[lane];
    float s = v.x+v.y;
    for (int o=32;o>0;o>>=1) s += __shfl_xor(s,o);
    float mean = s*(1.f/128.f);
    float dx=v.x-mean, dy=v.y-mean;
    float var = dx*dx+dy*dy;
    for (int o=32;o>0;o>>=1) var += __shfl_xor(var,o);
    float rs = rsqrtf(var*(1.f/128.f) + 1e-5f);
    float2 w2=((const float2*)w)[lane], b2=((const float2*)b)[lane];
    float yx = dx*rs*w2.x+b2.x, yy = dy*rs*w2.y+b2.y;
    ((unsigned*)y)[(size_t)r*64 + lane] = pk2bf(yx, yy);
}

// naive fp32 gemm for 12-row prefix. flags: 1=acc from out, 2=relu; base!=null adds base[idx]
__global__ __launch_bounds__(256) void small_gemm(const float* __restrict__ x, const float* __restrict__ W,
        const float* __restrict__ bias, float* __restrict__ out, const float* __restrict__ base,
        int R, int K, int NO, int flags){
    int idx = blockIdx.x*256 + threadIdx.x;
    if (idx >= R*NO) return;
    int r = idx / NO, n = idx - r*NO;
    const float4* xr = (const float4*)(x + (size_t)r*K);
    const float4* wr = (const float4*)(W + (size_t)n*K);
    float a = bias ? bias[n] : 0.0f;
    int K4 = K>>2;
    for (int k=0;k<K4;++k){
        float4 xv = xr[k], wv = wr[k];
        a += xv.x*wv.x + xv.y*wv.y + xv.z*wv.z + xv.w*wv.w;
    }
    if (flags & 2) a = fmaxf(a, 0.f);
    if (flags & 1) a += out[idx];
    if (base) a += base[idx];
    out[idx] = a;
}

__global__ __launch_bounds__(64) void self_attn12(const float* __restrict__ qkv, float* __restrict__ out){
    int hh = blockIdx.x;
    int lane = threadIdx.x;
    __shared__ float q[12][32], k[12][32], v[12][32], sc[12][12];
    for (int idx = lane; idx < 12*32; idx += 64){
        int c = idx>>5, d = idx&31;
        size_t base = (size_t)c*384 + hh*32 + d;
        q[c][d] = qkv[base] * 0.17677669529663687f;
        k[c][d] = qkv[base+128];
        v[c][d] = qkv[base+256];
    }
    __syncthreads();
    for (int p = lane; p < 144; p += 64){
        int qi = p/12, ki = p%12;
        float a = 0;
        #pragma unroll
        for (int d=0; d<32; ++d) a += q[qi][d]*k[ki][d];
        sc[qi][ki] = a;
    }
    __syncthreads();
    if (lane < 12){
        float m = -1e30f;
        for (int j=0;j<12;++j) m = fmaxf(m, sc[lane][j]);
        float sum=0;
        for (int j=0;j<12;++j){ float e=__expf(sc[lane][j]-m); sc[lane][j]=e; sum+=e; }
        float inv=1.f/sum;
        for (int j=0;j<12;++j) sc[lane][j]*=inv;
    }
    __syncthreads();
    for (int p = lane; p < 384; p += 64){
        int c = p>>5, d = p&31;
        float a=0;
        #pragma unroll
        for (int j=0;j<12;++j) a += sc[c][j]*v[j][d];
        out[(size_t)c*128 + hh*32 + d] = a;
    }
}

// ---------------- flash cross-attention, k-split, MFMA; shared q12 ----------------
__global__ __launch_bounds__(512) void cross_attn_part(const float* __restrict__ q12,
        const ushort_t* __restrict__ K, const ushort_t* __restrict__ V,
        float* __restrict__ opart, float2* __restrict__ mlpart){
    __shared__ __align__(16) ushort_t qs[16*136];
    __shared__ __align__(16) unsigned char uni[128*136*2];
    __shared__ __align__(16) ushort_t pbf[4*16*136];
    __shared__ float2 ml[48];
    float* s32 = (float*)uni;
    ushort_t* vt = (ushort_t*)uni;

    int tid = threadIdx.x;
    int b = blockIdx.x / NSPLIT, sp = blockIdx.x % NSPLIT;
    int k0 = sp * CHUNK;
    int lane = tid & 63, w = tid >> 6;
    int lr = lane & 15, hi8 = (lane >> 4) * 8;

    const unsigned* Vu = (const unsigned*)V + ((size_t)b*1000 + k0)*64;
    unsigned vreg[16];
    #pragma unroll
    for (int j=0;j<15;++j) vreg[j] = Vu[tid + j*512];
    if (tid < 320) vreg[15] = Vu[tid + 7680];

    for (int i = tid; i < 16*128; i += 512){
        int r = i >> 7, c = i & 127;
        ushort_t v = 0;
        if (r < 12) v = f2bf(q12[r*128 + c] * 0.17677669529663687f);
        qs[r*136 + c] = v;
    }
    for (int i = tid; i < 4352; i += 512) ((unsigned*)pbf)[i] = 0;
    __syncthreads();

    {
        int krow = k0 + w*16 + lr; if (krow > k0 + 124) krow = k0 + 124;
        const ushort_t* Krow = K + ((size_t)b*1000 + krow)*128 + hi8;
        #pragma unroll
        for (int h=0; h<4; ++h){
            short8 kf = *(const short8*)(Krow + h*32);
            short8 qf = *(const short8*)&qs[lr*136 + h*32 + hi8];
            f32x4 d = __builtin_amdgcn_mfma_f32_16x16x32_bf16(qf, kf, (f32x4){0,0,0,0}, 0, 0, 0);
            int qbase = (lane>>4)*4;
            #pragma unroll
            for (int r=0; r<4; ++r){
                int qq = qbase + r;
                if (qq < 12) s32[(h*12+qq)*130 + w*16 + lr] = d[r];
            }
        }
    }
    __syncthreads();

    if (tid < 192){
        int hq = tid >> 2, sub = tid & 3;
        int h = hq / 12, qq = hq - h*12;
        float m = -1e30f;
        for (int kk = sub; kk < CHUNK; kk += 4) m = fmaxf(m, s32[hq*130 + kk]);
        m = fmaxf(m, __shfl_xor(m, 1));
        m = fmaxf(m, __shfl_xor(m, 2));
        float l = 0.f;
        for (int kk = sub; kk < CHUNK; kk += 4){
            float e = __expf(s32[hq*130 + kk] - m);
            l += e;
            pbf[(h*16+qq)*136 + kk] = f2bf(e);
        }
        l += __shfl_xor(l, 1);
        l += __shfl_xor(l, 2);
        if (sub == 0) ml[hq] = make_float2(m, l);
    }
    __syncthreads();

    #pragma unroll
    for (int j=0;j<15;++j){
        int i = tid + j*512;
        int kk = i >> 6, dp = (i & 63)*2;
        unsigned u = vreg[j];
        vt[dp*136 + kk]     = (ushort_t)(u & 0xFFFF);
        vt[(dp+1)*136 + kk] = (ushort_t)(u >> 16);
    }
    if (tid < 320){
        int i = tid + 7680;
        int kk = i >> 6, dp = (i & 63)*2;
        unsigned u = vreg[15];
        vt[dp*136 + kk]     = (ushort_t)(u & 0xFFFF);
        vt[(dp+1)*136 + kk] = (ushort_t)(u >> 16);
    }
    if (tid < 384){
        int dp = tid / 3, kk = 125 + tid % 3;
        vt[dp*136 + kk] = 0;
    }
    __syncthreads();

    {
        int h = w >> 1;
        f32x4 acc = (f32x4){0,0,0,0};
        #pragma unroll
        for (int kc=0; kc<4; ++kc){
            short8 pf = *(const short8*)&pbf[(h*16+lr)*136 + kc*32 + hi8];
            short8 vf = *(const short8*)&vt[(w*16+lr)*136 + kc*32 + hi8];
            acc = __builtin_amdgcn_mfma_f32_16x16x32_bf16(pf, vf, acc, 0, 0, 0);
        }
        int qbase = (lane>>4)*4;
        float* ob = opart + ((size_t)(b*NSPLIT+sp)*12)*128;
        #pragma unroll
        for (int r=0; r<4; ++r){
            int qq = qbase + r;
            if (qq < 12) ob[(size_t)qq*128 + w*16 + lr] = acc[r];
        }
    }
    if (tid < 48) mlpart[(size_t)(b*NSPLIT+sp)*48 + tid] = ml[tid];
}

__global__ __launch_bounds__(256) void cross_attn_comb(const float* __restrict__ opart,
        const float* __restrict__ mlpart, ushort_t* __restrict__ attbf){
    int b = blockIdx.x, tid = threadIdx.x;
    __shared__ float mls[NSPLIT*48*2];
    for (int i = tid; i < NSPLIT*48*2; i += 256) mls[i] = mlpart[(size_t)b*NSPLIT*96 + i];
    __syncthreads();
    for (int p = tid; p < 1536; p += 256){
        int qq = p >> 7, dp = p & 127, h = dp >> 5, hq = h*12 + qq;
        float M = -1e30f;
        #pragma unroll
        for (int sp=0; sp<NSPLIT; ++sp) M = fmaxf(M, mls[sp*96 + hq*2]);
        float L = 0.f, O = 0.f;
        #pragma unroll
        for (int sp=0; sp<NSPLIT; ++sp){
            float wgt = __expf(mls[sp*96 + hq*2] - M);
            L += wgt * mls[sp*96 + hq*2 + 1];
            O += wgt * opart[((size_t)(b*NSPLIT+sp)*12 + qq)*128 + dp];
        }
        attbf[((size_t)b*12 + qq)*128 + dp] = f2bf(O / L);
    }
}

__global__ __launch_bounds__(256) void final_out(const float* __restrict__ t,
        const float* __restrict__ lw, const float* __restrict__ lb,
        const float* __restrict__ ow, const float* __restrict__ ob, float* __restrict__ out){
    int r = blockIdx.x*4 + (threadIdx.x>>6);
    int lane = threadIdx.x & 63;
    const float2* x2 = (const float2*)(t + (size_t)r*128);
    float2 v = x2[lane];
    float s = v.x+v.y;
    for (int o=32;o>0;o>>=1) s += __shfl_xor(s,o);
    float mean = s*(1.f/128.f);
    float dx=v.x-mean, dy=v.y-mean;
    float var = dx*dx+dy*dy;
    for (int o=32;o>0;o>>=1) var += __shfl_xor(var,o);
    float rs = rsqrtf(var*(1.f/128.f)+1e-5f);
    float2 w2=((const float2*)lw)[lane], b2=((const float2*)lb)[lane];
    float2 o2=((const float2*)ow)[lane];
    float d = (dx*rs*w2.x+b2.x)*o2.x + (dy*rs*w2.y+b2.y)*o2.y;
    for (int o=32;o>0;o>>=1) d += __shfl_xor(d,o);
    if (lane==0) out[r] = d + ob[0];
}

extern "C" void kernel_launch(void* const* d_in, const int* in_sizes, int n_in,
                              void* d_out, int out_size, void* d_ws, size_t ws_size,
                              hipStream_t stream){
    (void)in_sizes; (void)n_in; (void)out_size; (void)ws_size;
    const float* x        = (const float*)d_in[0];
    const int*   eidx     = (const int*)d_in[1];
    const float* in_w     = (const float*)d_in[3];
    const float* in_b     = (const float*)d_in[4];
    const float* gcn_w    = (const float*)d_in[5];
    const float* gcn_b    = (const float*)d_in[6];
    const float* ln_w     = (const float*)d_in[7];
    const float* ln_b     = (const float*)d_in[8];
    const float* cq       = (const float*)d_in[9];
    const float* sa_qkv_w = (const float*)d_in[10];
    const float* sa_qkv_b = (const float*)d_in[11];
    const float* sa_out_w = (const float*)d_in[12];
    const float* sa_out_b = (const float*)d_in[13];
    const float* ca_qkv_w = (const float*)d_in[14];
    const float* ca_qkv_b = (const float*)d_in[15];
    const float* ca_out_w = (const float*)d_in[16];
    const float* ca_out_b = (const float*)d_in[17];
    const float* n1w=(const float*)d_in[18]; const float* n1b=(const float*)d_in[19];
    const float* n2w=(const float*)d_in[20]; const float* n2b=(const float*)d_in[21];
    const float* n3w=(const float*)d_in[22]; const float* n3b=(const float*)d_in[23];
    const float* ff1w=(const float*)d_in[24]; const float* ff1b=(const float*)d_in[25];
    const float* ff2w=(const float*)d_in[26]; const float* ff2b=(const float*)d_in[27];
    const float* opln_w=(const float*)d_in[28]; const float* opln_b=(const float*)d_in[29];
    const float* opw=(const float*)d_in[30]; const float* opb=(const float*)d_in[31];
    float* out = (float*)d_out;

    char* base = (char*)d_ws;
    size_t off = 0;
    auto alloc = [&](size_t bytes)->void*{
        void* r = base + off; off += (bytes + 255) & ~(size_t)255; return r;
    };
    ushort_t* hbf   = (ushort_t*)alloc((size_t)NNODES*DD*2);
    ushort_t* kbf   = (ushort_t*)alloc((size_t)NNODES*DD*2);  // also hwbf during GCN loop
    ushort_t* vbf   = (ushort_t*)alloc((size_t)NNODES*DD*2);
    ushort_t* Wb    = (ushort_t*)alloc((size_t)5*DD*DD*2);
    ushort_t* Wpad  = (ushort_t*)alloc((size_t)DD*32*2);
    ushort_t* Wdec  = (ushort_t*)alloc((size_t)147456*2);
    float*    dinv  = (float*)alloc((size_t)NNODES*4);
    int*      cnt   = (int*)  alloc((size_t)NNODES*4);
    int*      offs  = (int*)  alloc((size_t)(NNODES+1)*4);
    int*      bsum  = (int*)  alloc(512*4);
    int2*     ee    = (int2*) alloc((size_t)NEDGES*8);
    float*    t12   = (float*)alloc((size_t)12*DD*4);
    float*    tn12  = (float*)alloc((size_t)12*DD*4);
    float*    sq12  = (float*)alloc((size_t)12*384*4);
    float*    att12 = (float*)alloc((size_t)12*DD*4);
    float*    q12   = (float*)alloc((size_t)12*DD*4);
    float*    tfull = (float*)alloc((size_t)NROWS*DD*4);
    ushort_t* tnbf  = (ushort_t*)alloc((size_t)NROWS*DD*2);
    ushort_t* attbf = (ushort_t*)alloc((size_t)NROWS*DD*2);
    ushort_t* ffhbf = (ushort_t*)alloc((size_t)NROWS*512*2);
    float*    opart = (float*)alloc((size_t)BB*NSPLIT*12*128*4);
    float2*   mlprt = (float2*)alloc((size_t)BB*NSPLIT*48*8);
    ushort_t* hwbf  = kbf;

    const int* erow = eidx;
    const int* ecol = eidx + NEDGES;

    // CSR build (once, reused by all 3 GCN layers)
    hipMemsetAsync(cnt, 0, (size_t)NNODES*4, stream);
    count_edges<<<NEDGES/256, 256, 0, stream>>>(ecol, cnt);
    scan_a<<<NNODES/256, 256, 0, stream>>>(cnt, offs, bsum, dinv);
    scan_b<<<1, 512, 0, stream>>>(bsum, NNODES/256);
    scan_c<<<NNODES/256, 256, 0, stream>>>(offs, bsum);
    hipMemsetAsync(cnt, 0, (size_t)NNODES*4, stream);
    fill_csr<<<NEDGES/256, 256, 0, stream>>>(erow, ecol, offs, cnt, dinv, ee);

    conv_all<<<912, 256, 0, stream>>>(gcn_w, ca_qkv_w, in_w, ca_out_w, ff1w, ff2w, Wb, Wpad, Wdec);

    // node pipeline (residual lives in hbf as bf16)
    in_proj_mfma<<<NNODES/64, 256, 0, stream>>>(x, Wpad, in_b, hbf);
    for (int i=0;i<3;++i){
        gemm_mfma<<<NNODES/64, 256, 0, stream>>>(hbf, Wb + (size_t)i*DD*DD, nullptr, hwbf);
        gcn_agg<<<NNODES/16, 256, 0, stream>>>(hbf, hwbf, offs, ee, dinv,
                gcn_b + (size_t)i*DD, ln_w + (size_t)i*DD, ln_b + (size_t)i*DD, i==2);
    }
    // fused cross-attn K+V projections (A read once)
    gemm_mfma_kv<<<NNODES/64, 256, 0, stream>>>(hbf, Wb + (size_t)3*DD*DD, Wb + (size_t)4*DD*DD,
            ca_qkv_b + DD, ca_qkv_b + 2*DD, kbf, vbf);

    // ---- decoder: batch-invariant 12-row prefix (fp32, exact, multi-launch) ----
    ln_rows<<<3, 256, 0, stream>>>(cq, tn12, n1w, n1b);
    small_gemm<<<18, 256, 0, stream>>>(tn12, sa_qkv_w, sa_qkv_b, sq12, nullptr, 12, 128, 384, 0);
    self_attn12<<<4, 64, 0, stream>>>(sq12, att12);
    small_gemm<<<6, 256, 0, stream>>>(att12, sa_out_w, sa_out_b, t12, cq, 12, 128, 128, 0);
    ln_rows<<<3, 256, 0, stream>>>(t12, tn12, n2w, n2b);
    small_gemm<<<6, 256, 0, stream>>>(tn12, ca_qkv_w, ca_qkv_b, q12, nullptr, 12, 128, 128, 0);

    // ---- per-batch: cross-attention + FF (bf16 MFMA) ----
    cross_attn_part<<<BB*NSPLIT, 512, 0, stream>>>(q12, kbf, vbf, opart, mlprt);
    cross_attn_comb<<<BB, 256, 0, stream>>>(opart, (const float*)mlprt, attbf);
    dim3 g24_1(24,1), g24_4(24,4);
    dec_gemm<<<g24_1, 256, 0, stream>>>(attbf, Wdec, ca_out_b, tfull, nullptr, t12, 128, 128, 16|8);
    ln_rows_bf<<<NROWS/4, 256, 0, stream>>>(tfull, tnbf, n3w, n3b);
    dec_gemm<<<g24_4, 256, 0, stream>>>(tnbf, Wdec + 16384, ff1b, nullptr, ffhbf, nullptr, 128, 512, 2|4);
    dec_gemm<<<g24_1, 256, 0, stream>>>(ffhbf, Wdec + 81920, ff2b, tfull, nullptr, nullptr, 512, 128, 1|8);
    final_out<<<NROWS/4, 256, 0, stream>>>(tfull, opln_w, opln_b, opw, opb, out);
}

// Round 19
// 407.173 us; speedup vs baseline: 1.0604x; 1.0165x over previous
//
#include <hip/hip_runtime.h>
#include <hip/hip_bf16.h>

#define NNODES 128000
#define NEDGES 640000
#define BB 128
#define CC 12
#define DD 128
#define NROWS (BB*CC)   // 1536
#define NSPLIT 8
#define CHUNK 125

typedef __attribute__((ext_vector_type(8))) short short8;
typedef __attribute__((ext_vector_type(4))) float f32x4;
typedef unsigned short ushort_t;

__device__ __forceinline__ unsigned pk2bf(float lo, float hi){
    union { __hip_bfloat162 h; unsigned u; } v;
    v.h = __float22bfloat162_rn(make_float2(lo, hi));
    return v.u;
}
__device__ __forceinline__ ushort_t f2bf(float f){
    union { __hip_bfloat16 h; ushort_t u; } v;
    v.h = __float2bfloat16(f);
    return v.u;
}
__device__ __forceinline__ float bfu_lo(unsigned u){
    union { unsigned u; float f; } v; v.u = u << 16; return v.f;
}
__device__ __forceinline__ float bfu_hi(unsigned u){
    union { unsigned u; float f; } v; v.u = u & 0xFFFF0000u; return v.f;
}

// ---------------- CSR build ----------------
__global__ __launch_bounds__(256) void count_edges(const int* __restrict__ col, int* __restrict__ cnt){
    int e = blockIdx.x*256 + threadIdx.x;
    if (e < NEDGES) atomicAdd(&cnt[col[e]], 1);
}

// scan_a also emits dinv (reads cnt anyway)
__global__ __launch_bounds__(256) void scan_a(const int* __restrict__ cnt, int* __restrict__ offs,
        int* __restrict__ bsum, float* __restrict__ dinv){
    __shared__ int tmp[256];
    int tid = threadIdx.x;
    int g = blockIdx.x*256 + tid;
    int v = cnt[g];
    dinv[g] = rsqrtf((float)v + 1.0f);
    tmp[tid] = v;
    __syncthreads();
    for (int o=1;o<256;o<<=1){
        int a = (tid>=o)? tmp[tid-o] : 0;
        __syncthreads();
        tmp[tid] += a;
        __syncthreads();
    }
    offs[g] = tmp[tid] - v;
    if (tid==255) bsum[blockIdx.x] = tmp[255];
}

__global__ __launch_bounds__(512) void scan_b(int* __restrict__ bsum, int NB){
    __shared__ int tmp[512];
    int tid = threadIdx.x;
    int v = (tid<NB)? bsum[tid] : 0;
    tmp[tid] = v;
    __syncthreads();
    for (int o=1;o<512;o<<=1){
        int a = (tid>=o)? tmp[tid-o] : 0;
        __syncthreads();
        tmp[tid] += a;
        __syncthreads();
    }
    if (tid<NB) bsum[tid] = tmp[tid] - v;
}

__global__ __launch_bounds__(256) void scan_c(int* __restrict__ offs, const int* __restrict__ bsum){
    int g = blockIdx.x*256 + threadIdx.x;
    offs[g] += bsum[g>>8];
    if (g==0) offs[NNODES] = NEDGES;
}

__global__ __launch_bounds__(256) void fill_csr(const int* __restrict__ row, const int* __restrict__ col,
        const int* __restrict__ offs, int* __restrict__ cur, const float* __restrict__ dinv,
        int2* __restrict__ ee){
    int e = blockIdx.x*256 + threadIdx.x;
    if (e >= NEDGES) return;
    int c = col[e], r = row[e];
    int p = atomicAdd(&cur[c], 1);
    int idx = offs[c] + p;
    float w = dinv[r]*dinv[c];
    ee[idx] = make_int2(r, __float_as_int(w));
}

// ---------------- all weight conversions in one kernel ----------------
__global__ __launch_bounds__(256) void conv_all(const float* __restrict__ gcn_w,
        const float* __restrict__ ca_qkv_w, const float* __restrict__ in_w,
        const float* __restrict__ caout, const float* __restrict__ ff1, const float* __restrict__ ff2,
        ushort_t* __restrict__ Wb, ushort_t* __restrict__ Wpad, ushort_t* __restrict__ Wd){
    int i = blockIdx.x*256 + threadIdx.x;   // < 233472
    if (i < 81920){
        int slot = i >> 14, off = i & 16383;
        float v = (slot < 3) ? gcn_w[slot*16384 + off]
                             : ca_qkv_w[16384 + (slot-3)*16384 + off];
        Wb[i] = f2bf(v);
    } else if (i < 86016){
        int j = i - 81920;
        int n = j >> 5, k = j & 31;
        Wpad[j] = (k < 16) ? f2bf(in_w[n*16 + k]) : (ushort_t)0;
    } else {
        int j = i - 86016;   // < 147456
        float v;
        if (j < 16384) v = caout[j];
        else if (j < 81920) v = ff1[j - 16384];
        else v = ff2[j - 81920];
        Wd[j] = f2bf(v);
    }
}

// ---------------- fused input projection + GCN layer-0 GEMM ----------------
// stage 1: h = x @ in_w.T + b (MFMA, swapped operands) -> hbf global + LDS tile
// stage 2: hw0 = h @ W0.T (v2 two-phase W staging, A from LDS)
__global__ __launch_bounds__(256) void in_proj_gemm0(const float* __restrict__ x,
        const ushort_t* __restrict__ Wpad, const float* __restrict__ bias,
        const ushort_t* __restrict__ W0, ushort_t* __restrict__ hbf, ushort_t* __restrict__ hwbf){
    __shared__ __align__(16) ushort_t xs[64*40];
    __shared__ __align__(16) ushort_t hs[64*132];
    __shared__ __align__(16) ushort_t wl[64*132];
    int tid = threadIdx.x;
    int m0 = blockIdx.x*64;
    // ---- stage 1: input projection ----
    if (tid < 128){
        short8 z = {0,0,0,0,0,0,0,0};
        *(short8*)&xs[(tid>>1)*40 + 16 + (tid&1)*8] = z;
    }
    float4 xv = *(const float4*)(x + (size_t)m0*16 + tid*4);
    uint2 pk2;
    pk2.x = pk2bf(xv.x, xv.y);
    pk2.y = pk2bf(xv.z, xv.w);
    *(uint2*)&xs[(tid>>2)*40 + (tid&3)*4] = pk2;
    __syncthreads();
    int lane = tid & 63, wave = tid >> 6;
    int lr = lane & 15, hi4 = lane >> 4, lk = hi4*8;
    {
        short8 wf[8];
        #pragma unroll
        for (int nt=0; nt<8; ++nt)
            wf[nt] = *(const short8*)&Wpad[(nt*16 + lr)*32 + lk];
        short8 a = *(const short8*)&xs[(wave*16 + lr)*40 + lk];
        f32x4 acc[8];
        #pragma unroll
        for (int nt=0; nt<8; ++nt)
            acc[nt] = __builtin_amdgcn_mfma_f32_16x16x32_bf16(wf[nt], a, (f32x4){0,0,0,0}, 0, 0, 0);
        size_t m = (size_t)m0 + wave*16 + lr;
        int lm = wave*16 + lr;
        #pragma unroll
        for (int nt=0; nt<8; ++nt){
            int n0 = nt*16 + hi4*4;
            float4 bv = *(const float4*)&bias[n0];
            uint2 pk;
            pk.x = pk2bf(acc[nt][0]+bv.x, acc[nt][1]+bv.y);
            pk.y = pk2bf(acc[nt][2]+bv.z, acc[nt][3]+bv.w);
            *(uint2*)&hbf[m*128 + n0] = pk;
            *(uint2*)&hs[lm*132 + n0] = pk;
        }
    }
    __syncthreads();
    // ---- stage 2: gemm0 (A from LDS) ----
    short8 h[4];
    #pragma unroll
    for (int kc=0;kc<4;++kc)
        h[kc] = *(const short8*)&hs[(wave*16 + lr)*132 + kc*32 + lk];
    f32x4 acc[8];
    #pragma unroll
    for (int j=0;j<8;++j) acc[j] = (f32x4){0.f,0.f,0.f,0.f};
    #pragma unroll
    for (int ph=0; ph<2; ++ph){
        if (ph) __syncthreads();
        #pragma unroll
        for (int i=0;i<4;++i){
            int e = tid*8 + i*2048;
            int row = e >> 7, k = e & 127;
            *(short8*)&wl[row*132 + k] = *(const short8*)&W0[(ph*64 + row)*128 + k];
        }
        __syncthreads();
        #pragma unroll
        for (int kc=0; kc<4; ++kc){
            #pragma unroll
            for (int nt=0; nt<4; ++nt){
                short8 wf = *(const short8*)&wl[(nt*16 + lr)*132 + kc*32 + lk];
                acc[ph*4+nt] = __builtin_amdgcn_mfma_f32_16x16x32_bf16(wf, h[kc], acc[ph*4+nt], 0, 0, 0);
            }
        }
    }
    size_t m = (size_t)m0 + wave*16 + lr;
    #pragma unroll
    for (int j=0; j<8; ++j){
        int n0 = j*16 + hi4*4;
        uint2 pk;
        pk.x = pk2bf(acc[j][0], acc[j][1]);
        pk.y = pk2bf(acc[j][2], acc[j][3]);
        *(uint2*)&hwbf[m*128 + n0] = pk;
    }
}

// ---------------- MFMA GEMM v2: 16 rows/wave, 64-row blocks, half-W staging ----------------
__global__ __launch_bounds__(256) void gemm_mfma(const ushort_t* __restrict__ A,
        const ushort_t* __restrict__ Wb, const float* __restrict__ bias, ushort_t* __restrict__ out){
    __shared__ __align__(16) ushort_t wl[64*132];
    int tid = threadIdx.x;
    int lane = tid & 63, wave = tid >> 6;
    int m0 = blockIdx.x*64 + wave*16;
    int lr = lane & 15, hi4 = lane >> 4;
    int lk = hi4 * 8;
    const ushort_t* arow = A + (size_t)(m0 + lr)*128 + lk;
    short8 h[4];
    #pragma unroll
    for (int kc=0;kc<4;++kc) h[kc] = *(const short8*)(arow + kc*32);
    f32x4 acc[8];
    #pragma unroll
    for (int j=0;j<8;++j) acc[j] = (f32x4){0.f,0.f,0.f,0.f};
    #pragma unroll
    for (int ph=0; ph<2; ++ph){
        if (ph) __syncthreads();
        #pragma unroll
        for (int i=0;i<4;++i){
            int e = tid*8 + i*2048;
            int row = e >> 7, k = e & 127;
            *(short8*)&wl[row*132 + k] = *(const short8*)&Wb[(ph*64 + row)*128 + k];
        }
        __syncthreads();
        #pragma unroll
        for (int kc=0; kc<4; ++kc){
            #pragma unroll
            for (int nt=0; nt<4; ++nt){
                short8 wf = *(const short8*)&wl[(nt*16 + lr)*132 + kc*32 + lk];
                acc[ph*4+nt] = __builtin_amdgcn_mfma_f32_16x16x32_bf16(wf, h[kc], acc[ph*4+nt], 0, 0, 0);
            }
        }
    }
    size_t m = (size_t)m0 + lr;
    #pragma unroll
    for (int j=0; j<8; ++j){
        int n0 = j*16 + hi4*4;
        float b0=0.f,b1=0.f,b2=0.f,b3=0.f;
        if (bias){
            float4 bv = *(const float4*)&bias[n0];
            b0=bv.x; b1=bv.y; b2=bv.z; b3=bv.w;
        }
        uint2 pk;
        pk.x = pk2bf(acc[j][0]+b0, acc[j][1]+b1);
        pk.y = pk2bf(acc[j][2]+b2, acc[j][3]+b3);
        *(uint2*)&out[m*128 + n0] = pk;
    }
}

// ---------------- fused K+V GEMM v2: 16 rows/wave, half-W staging, acc reused K->V ----------
__global__ __launch_bounds__(256) void gemm_mfma_kv(const ushort_t* __restrict__ A,
        const ushort_t* __restrict__ Wk, const ushort_t* __restrict__ Wv,
        const float* __restrict__ bk, const float* __restrict__ bv,
        ushort_t* __restrict__ outk, ushort_t* __restrict__ outv){
    __shared__ __align__(16) ushort_t wl[64*132];
    int tid = threadIdx.x;
    int lane = tid & 63, wave = tid >> 6;
    int m0 = blockIdx.x*64 + wave*16;
    int lr = lane & 15, hi4 = lane >> 4;
    int lk = hi4 * 8;
    const ushort_t* arow = A + (size_t)(m0 + lr)*128 + lk;
    short8 h[4];
    #pragma unroll
    for (int kc=0;kc<4;++kc) h[kc] = *(const short8*)(arow + kc*32);
    size_t m = (size_t)m0 + lr;
    f32x4 acc[8];
    // ---- K ----
    #pragma unroll
    for (int j=0;j<8;++j) acc[j] = (f32x4){0.f,0.f,0.f,0.f};
    #pragma unroll
    for (int ph=0; ph<2; ++ph){
        if (ph) __syncthreads();
        #pragma unroll
        for (int i=0;i<4;++i){
            int e = tid*8 + i*2048;
            int row = e >> 7, k = e & 127;
            *(short8*)&wl[row*132 + k] = *(const short8*)&Wk[(ph*64 + row)*128 + k];
        }
        __syncthreads();
        #pragma unroll
        for (int kc=0; kc<4; ++kc){
            #pragma unroll
            for (int nt=0; nt<4; ++nt){
                short8 wf = *(const short8*)&wl[(nt*16 + lr)*132 + kc*32 + lk];
                acc[ph*4+nt] = __builtin_amdgcn_mfma_f32_16x16x32_bf16(wf, h[kc], acc[ph*4+nt], 0, 0, 0);
            }
        }
    }
    #pragma unroll
    for (int j=0; j<8; ++j){
        int n0 = j*16 + hi4*4;
        float4 bv4 = *(const float4*)&bk[n0];
        uint2 pk;
        pk.x = pk2bf(acc[j][0]+bv4.x, acc[j][1]+bv4.y);
        pk.y = pk2bf(acc[j][2]+bv4.z, acc[j][3]+bv4.w);
        *(uint2*)&outk[m*128 + n0] = pk;
    }
    // ---- V ----
    #pragma unroll
    for (int j=0;j<8;++j) acc[j] = (f32x4){0.f,0.f,0.f,0.f};
    #pragma unroll
    for (int ph=0; ph<2; ++ph){
        __syncthreads();
        #pragma unroll
        for (int i=0;i<4;++i){
            int e = tid*8 + i*2048;
            int row = e >> 7, k = e & 127;
            *(short8*)&wl[row*132 + k] = *(const short8*)&Wv[(ph*64 + row)*128 + k];
        }
        __syncthreads();
        #pragma unroll
        for (int kc=0; kc<4; ++kc){
            #pragma unroll
            for (int nt=0; nt<4; ++nt){
                short8 wf = *(const short8*)&wl[(nt*16 + lr)*132 + kc*32 + lk];
                acc[ph*4+nt] = __builtin_amdgcn_mfma_f32_16x16x32_bf16(wf, h[kc], acc[ph*4+nt], 0, 0, 0);
            }
        }
    }
    #pragma unroll
    for (int j=0; j<8; ++j){
        int n0 = j*16 + hi4*4;
        float4 bv4 = *(const float4*)&bv[n0];
        uint2 pk;
        pk.x = pk2bf(acc[j][0]+bv4.x, acc[j][1]+bv4.y);
        pk.y = pk2bf(acc[j][2]+bv4.z, acc[j][3]+bv4.w);
        *(uint2*)&outv[m*128 + n0] = pk;
    }
}

// ---------------- GCN aggregate: 4 nodes/wave (16 lanes x uint4), 4-deep loop + LN ----------
__global__ __launch_bounds__(256) void gcn_agg(ushort_t* __restrict__ hbf, const ushort_t* __restrict__ hwbf,
        const int* __restrict__ offs, const int2* __restrict__ ee,
        const float* __restrict__ dinv, const float* __restrict__ bias,
        const float* __restrict__ lnw, const float* __restrict__ lnb, int last){
    int wave = threadIdx.x >> 6;
    int lane = threadIdx.x & 63;
    int g = lane >> 4, sl = lane & 15;
    int node = blockIdx.x*16 + wave*4 + g;
    const uint4* hwu = (const uint4*)hwbf;
    uint4* hbu = (uint4*)hbf;
    uint4 sv = hwu[(size_t)node*16 + sl];
    uint4 rv = make_uint4(0,0,0,0);
    if (!last) rv = hbu[(size_t)node*16 + sl];
    float di = dinv[node];
    float sw = di*di;
    float a0 = sw*bfu_lo(sv.x), a1 = sw*bfu_hi(sv.x);
    float a2 = sw*bfu_lo(sv.y), a3 = sw*bfu_hi(sv.y);
    float a4 = sw*bfu_lo(sv.z), a5 = sw*bfu_hi(sv.z);
    float a6 = sw*bfu_lo(sv.w), a7 = sw*bfu_hi(sv.w);
    float b0=0,b1=0,b2=0,b3=0,b4=0,b5=0,b6=0,b7=0;
    int e0 = offs[node], e1 = offs[node+1];
    int e = e0;
    for (; e + 4 <= e1; e += 4){
        int2 p0 = ee[e], p1 = ee[e+1], p2 = ee[e+2], p3 = ee[e+3];
        uint4 u0 = hwu[(size_t)p0.x*16 + sl];
        uint4 u1 = hwu[(size_t)p1.x*16 + sl];
        uint4 u2 = hwu[(size_t)p2.x*16 + sl];
        uint4 u3 = hwu[(size_t)p3.x*16 + sl];
        float w0 = __int_as_float(p0.y), w1 = __int_as_float(p1.y);
        float w2 = __int_as_float(p2.y), w3 = __int_as_float(p3.y);
        a0 += w0*bfu_lo(u0.x); a1 += w0*bfu_hi(u0.x); a2 += w0*bfu_lo(u0.y); a3 += w0*bfu_hi(u0.y);
        a4 += w0*bfu_lo(u0.z); a5 += w0*bfu_hi(u0.z); a6 += w0*bfu_lo(u0.w); a7 += w0*bfu_hi(u0.w);
        b0 += w1*bfu_lo(u1.x); b1 += w1*bfu_hi(u1.x); b2 += w1*bfu_lo(u1.y); b3 += w1*bfu_hi(u1.y);
        b4 += w1*bfu_lo(u1.z); b5 += w1*bfu_hi(u1.z); b6 += w1*bfu_lo(u1.w); b7 += w1*bfu_hi(u1.w);
        a0 += w2*bfu_lo(u2.x); a1 += w2*bfu_hi(u2.x); a2 += w2*bfu_lo(u2.y); a3 += w2*bfu_hi(u2.y);
        a4 += w2*bfu_lo(u2.z); a5 += w2*bfu_hi(u2.z); a6 += w2*bfu_lo(u2.w); a7 += w2*bfu_hi(u2.w);
        b0 += w3*bfu_lo(u3.x); b1 += w3*bfu_hi(u3.x); b2 += w3*bfu_lo(u3.y); b3 += w3*bfu_hi(u3.y);
        b4 += w3*bfu_lo(u3.z); b5 += w3*bfu_hi(u3.z); b6 += w3*bfu_lo(u3.w); b7 += w3*bfu_hi(u3.w);
    }
    if (e + 2 <= e1){
        int2 p0 = ee[e], p1 = ee[e+1];
        uint4 u0 = hwu[(size_t)p0.x*16 + sl];
        uint4 u1 = hwu[(size_t)p1.x*16 + sl];
        float w0 = __int_as_float(p0.y), w1 = __int_as_float(p1.y);
        a0 += w0*bfu_lo(u0.x); a1 += w0*bfu_hi(u0.x); a2 += w0*bfu_lo(u0.y); a3 += w0*bfu_hi(u0.y);
        a4 += w0*bfu_lo(u0.z); a5 += w0*bfu_hi(u0.z); a6 += w0*bfu_lo(u0.w); a7 += w0*bfu_hi(u0.w);
        b0 += w1*bfu_lo(u1.x); b1 += w1*bfu_hi(u1.x); b2 += w1*bfu_lo(u1.y); b3 += w1*bfu_hi(u1.y);
        b4 += w1*bfu_lo(u1.z); b5 += w1*bfu_hi(u1.z); b6 += w1*bfu_lo(u1.w); b7 += w1*bfu_hi(u1.w);
        e += 2;
    }
    if (e < e1){
        int2 p0 = ee[e];
        uint4 u0 = hwu[(size_t)p0.x*16 + sl];
        float w0 = __int_as_float(p0.y);
        a0 += w0*bfu_lo(u0.x); a1 += w0*bfu_hi(u0.x); a2 += w0*bfu_lo(u0.y); a3 += w0*bfu_hi(u0.y);
        a4 += w0*bfu_lo(u0.z); a5 += w0*bfu_hi(u0.z); a6 += w0*bfu_lo(u0.w); a7 += w0*bfu_hi(u0.w);
    }
    a0 += b0; a1 += b1; a2 += b2; a3 += b3;
    a4 += b4; a5 += b5; a6 += b6; a7 += b7;
    {
        const float4* b4p = (const float4*)bias;
        float4 bb0 = b4p[sl*2], bb1 = b4p[sl*2+1];
        a0 += bb0.x; a1 += bb0.y; a2 += bb0.z; a3 += bb0.w;
        a4 += bb1.x; a5 += bb1.y; a6 += bb1.z; a7 += bb1.w;
    }
    float s = ((a0+a1)+(a2+a3))+((a4+a5)+(a6+a7));
    s += __shfl_xor(s,1); s += __shfl_xor(s,2); s += __shfl_xor(s,4); s += __shfl_xor(s,8);
    float mean = s*(1.f/128.f);
    a0 -= mean; a1 -= mean; a2 -= mean; a3 -= mean;
    a4 -= mean; a5 -= mean; a6 -= mean; a7 -= mean;
    float var = ((a0*a0+a1*a1)+(a2*a2+a3*a3))+((a4*a4+a5*a5)+(a6*a6+a7*a7));
    var += __shfl_xor(var,1); var += __shfl_xor(var,2); var += __shfl_xor(var,4); var += __shfl_xor(var,8);
    float rs = rsqrtf(var*(1.f/128.f) + 1e-5f);
    float4 w0v = ((const float4*)lnw)[sl*2], w1v = ((const float4*)lnw)[sl*2+1];
    float4 l0v = ((const float4*)lnb)[sl*2], l1v = ((const float4*)lnb)[sl*2+1];
    float y0 = a0*rs*w0v.x + l0v.x;
    float y1 = a1*rs*w0v.y + l0v.y;
    float y2 = a2*rs*w0v.z + l0v.z;
    float y3 = a3*rs*w0v.w + l0v.w;
    float y4 = a4*rs*w1v.x + l1v.x;
    float y5 = a5*rs*w1v.y + l1v.y;
    float y6 = a6*rs*w1v.z + l1v.z;
    float y7 = a7*rs*w1v.w + l1v.w;
    if (!last){
        y0 = fmaxf(y0,0.f) + bfu_lo(rv.x);
        y1 = fmaxf(y1,0.f) + bfu_hi(rv.x);
        y2 = fmaxf(y2,0.f) + bfu_lo(rv.y);
        y3 = fmaxf(y3,0.f) + bfu_hi(rv.y);
        y4 = fmaxf(y4,0.f) + bfu_lo(rv.z);
        y5 = fmaxf(y5,0.f) + bfu_hi(rv.z);
        y6 = fmaxf(y6,0.f) + bfu_lo(rv.w);
        y7 = fmaxf(y7,0.f) + bfu_hi(rv.w);
    }
    uint4 pk;
    pk.x = pk2bf(y0, y1);
    pk.y = pk2bf(y2, y3);
    pk.z = pk2bf(y4, y5);
    pk.w = pk2bf(y6, y7);
    hbu[(size_t)node*16 + sl] = pk;
}

// ---------------- decoder MFMA GEMM: flexible K, NO via grid.y ----------------
// flags: 1=acc from out(fp32), 2=relu, 4=write outbf, 8=write out fp32, 16=acc from t12 bcast
__global__ __launch_bounds__(256) void dec_gemm(const ushort_t* __restrict__ A,
        const ushort_t* __restrict__ Wb, const float* __restrict__ bias,
        float* __restrict__ out, ushort_t* __restrict__ outbf,
        const float* __restrict__ tbc,
        int K, int NO, int flags){
    int lane = threadIdx.x & 63, wave = threadIdx.x >> 6;
    int m0 = blockIdx.x*64 + wave*16;
    int n0 = blockIdx.y*128;
    int lr = lane & 15, lk = (lane>>4)*8;
    f32x4 acc[8];
    #pragma unroll
    for (int nt=0; nt<8; ++nt) acc[nt] = (f32x4){0.f,0.f,0.f,0.f};
    for (int ko = 0; ko < K; ko += 128){
        short8 bfrag[4][8];
        #pragma unroll
        for (int nt=0; nt<8; ++nt)
            #pragma unroll
            for (int kc=0; kc<4; ++kc)
                bfrag[kc][nt] = *(const short8*)&Wb[(size_t)(n0 + nt*16 + lr)*K + ko + kc*32 + lk];
        const ushort_t* arow = A + (size_t)(m0 + lr)*K + ko + lk;
        #pragma unroll
        for (int kc=0; kc<4; ++kc){
            short8 a = *(const short8*)(arow + kc*32);
            #pragma unroll
            for (int nt=0; nt<8; ++nt)
                acc[nt] = __builtin_amdgcn_mfma_f32_16x16x32_bf16(a, bfrag[kc][nt], acc[nt], 0, 0, 0);
        }
    }
    int orow0 = m0 + (lane>>4)*4;
    #pragma unroll
    for (int nt=0; nt<8; ++nt){
        int col = n0 + nt*16 + lr;
        float bv = bias[col];
        #pragma unroll
        for (int r=0; r<4; ++r){
            int row = orow0 + r;
            size_t idx = (size_t)row*NO + col;
            float val = acc[nt][r] + bv;
            if (flags & 2) val = fmaxf(val, 0.f);
            if (flags & 1) val += out[idx];
            if (flags & 16) val += tbc[(row % 12)*128 + col];
            if (flags & 8) out[idx] = val;
            if (flags & 4) outbf[idx] = f2bf(val);
        }
    }
}

// ---------------- decoder small ops (multi-launch batch-invariant prefix) ----------------
__global__ __launch_bounds__(256) void ln_rows(const float* __restrict__ x, float* __restrict__ y,
        const float* __restrict__ w, const float* __restrict__ b){
    int r = blockIdx.x*4 + (threadIdx.x>>6);
    int lane = threadIdx.x & 63;
    const float2* x2 = (const float2*)(x + (size_t)r*128);
    float2 v = x2[lane];
    float s = v.x+v.y;
    for (int o=32;o>0;o>>=1) s += __shfl_xor(s,o);
    float mean = s*(1.f/128.f);
    float dx=v.x-mean, dy=v.y-mean;
    float var = dx*dx+dy*dy;
    for (int o=32;o>0;o>>=1) var += __shfl_xor(var,o);
    float rs = rsqrtf(var*(1.f/128.f) + 1e-5f);
    float2 w2=((const float2*)w)[lane], b2=((const float2*)b)[lane];
    ((float2*)(y + (size_t)r*128))[lane] = make_float2(dx*rs*w2.x+b2.x, dy*rs*w2.y+b2.y);
}

__global__ __launch_bounds__(256) void ln_rows_bf(const float* __restrict__ x, ushort_t* __restrict__ y,
        const float* __restrict__ w, const float* __restrict__ b){
    int r = blockIdx.x*4 + (threadIdx.x>>6);
    int lane = threadIdx.x & 63;
    const float2* x2 = (const float2*)(x + (size_t)r*128);
    float2 v = x2[lane];
    float s = v.x+v.y;
    for (int o=32;o>0;o>>=1) s += __shfl_xor(s,o);
    float mean = s*(1.f/128.f);
    float dx=v.x-mean, dy=v.y-mean;
    float var = dx*dx+dy*dy;
    for (int o=32;o>0;o>>=1) var += __shfl_xor(var,o);
    float rs = rsqrtf(var*(1.f/128.f) + 1e-5f);
    float2 w2=((const float2*)w)[lane], b2=((const float2*)b)[lane];
    float yx = dx*rs*w2.x+b2.x, yy = dy*rs*w2.y+b2.y;
    ((unsigned*)y)[(size_t)r*64 + lane] = pk2bf(yx, yy);
}

// naive fp32 gemm for 12-row prefix. flags: 1=acc from out, 2=relu; base!=null adds base[idx]
__global__ __launch_bounds__(256) void small_gemm(const float* __restrict__ x, const float* __restrict__ W,
        const float* __restrict__ bias, float* __restrict__ out, const float* __restrict__ base,
        int R, int K, int NO, int flags){
    int idx = blockIdx.x*256 + threadIdx.x;
    if (idx >= R*NO) return;
    int r = idx / NO, n = idx - r*NO;
    const float4* xr = (const float4*)(x + (size_t)r*K);
    const float4* wr = (const float4*)(W + (size_t)n*K);
    float a = bias ? bias[n] : 0.0f;
    int K4 = K>>2;
    for (int k=0;k<K4;++k){
        float4 xv = xr[k], wv = wr[k];
        a += xv.x*wv.x + xv.y*wv.y + xv.z*wv.z + xv.w*wv.w;
    }
    if (flags & 2) a = fmaxf(a, 0.f);
    if (flags & 1) a += out[idx];
    if (base) a += base[idx];
    out[idx] = a;
}

__global__ __launch_bounds__(64) void self_attn12(const float* __restrict__ qkv, float* __restrict__ out){
    int hh = blockIdx.x;
    int lane = threadIdx.x;
    __shared__ float q[12][32], k[12][32], v[12][32], sc[12][12];
    for (int idx = lane; idx < 12*32; idx += 64){
        int c = idx>>5, d = idx&31;
        size_t base = (size_t)c*384 + hh*32 + d;
        q[c][d] = qkv[base] * 0.17677669529663687f;
        k[c][d] = qkv[base+128];
        v[c][d] = qkv[base+256];
    }
    __syncthreads();
    for (int p = lane; p < 144; p += 64){
        int qi = p/12, ki = p%12;
        float a = 0;
        #pragma unroll
        for (int d=0; d<32; ++d) a += q[qi][d]*k[ki][d];
        sc[qi][ki] = a;
    }
    __syncthreads();
    if (lane < 12){
        float m = -1e30f;
        for (int j=0;j<12;++j) m = fmaxf(m, sc[lane][j]);
        float sum=0;
        for (int j=0;j<12;++j){ float e=__expf(sc[lane][j]-m); sc[lane][j]=e; sum+=e; }
        float inv=1.f/sum;
        for (int j=0;j<12;++j) sc[lane][j]*=inv;
    }
    __syncthreads();
    for (int p = lane; p < 384; p += 64){
        int c = p>>5, d = p&31;
        float a=0;
        #pragma unroll
        for (int j=0;j<12;++j) a += sc[c][j]*v[j][d];
        out[(size_t)c*128 + hh*32 + d] = a;
    }
}

// ---------------- flash cross-attention, k-split, MFMA; shared q12 ----------------
__global__ __launch_bounds__(512) void cross_attn_part(const float* __restrict__ q12,
        const ushort_t* __restrict__ K, const ushort_t* __restrict__ V,
        float* __restrict__ opart, float2* __restrict__ mlpart){
    __shared__ __align__(16) ushort_t qs[16*136];
    __shared__ __align__(16) unsigned char uni[128*136*2];
    __shared__ __align__(16) ushort_t pbf[4*16*136];
    __shared__ float2 ml[48];
    float* s32 = (float*)uni;
    ushort_t* vt = (ushort_t*)uni;

    int tid = threadIdx.x;
    int b = blockIdx.x / NSPLIT, sp = blockIdx.x % NSPLIT;
    int k0 = sp * CHUNK;
    int lane = tid & 63, w = tid >> 6;
    int lr = lane & 15, hi8 = (lane >> 4) * 8;

    const unsigned* Vu = (const unsigned*)V + ((size_t)b*1000 + k0)*64;
    unsigned vreg[16];
    #pragma unroll
    for (int j=0;j<15;++j) vreg[j] = Vu[tid + j*512];
    if (tid < 320) vreg[15] = Vu[tid + 7680];

    for (int i = tid; i < 16*128; i += 512){
        int r = i >> 7, c = i & 127;
        ushort_t v = 0;
        if (r < 12) v = f2bf(q12[r*128 + c] * 0.17677669529663687f);
        qs[r*136 + c] = v;
    }
    for (int i = tid; i < 4352; i += 512) ((unsigned*)pbf)[i] = 0;
    __syncthreads();

    {
        int krow = k0 + w*16 + lr; if (krow > k0 + 124) krow = k0 + 124;
        const ushort_t* Krow = K + ((size_t)b*1000 + krow)*128 + hi8;
        #pragma unroll
        for (int h=0; h<4; ++h){
            short8 kf = *(const short8*)(Krow + h*32);
            short8 qf = *(const short8*)&qs[lr*136 + h*32 + hi8];
            f32x4 d = __builtin_amdgcn_mfma_f32_16x16x32_bf16(qf, kf, (f32x4){0,0,0,0}, 0, 0, 0);
            int qbase = (lane>>4)*4;
            #pragma unroll
            for (int r=0; r<4; ++r){
                int qq = qbase + r;
                if (qq < 12) s32[(h*12+qq)*130 + w*16 + lr] = d[r];
            }
        }
    }
    __syncthreads();

    if (tid < 192){
        int hq = tid >> 2, sub = tid & 3;
        int h = hq / 12, qq = hq - h*12;
        float m = -1e30f;
        for (int kk = sub; kk < CHUNK; kk += 4) m = fmaxf(m, s32[hq*130 + kk]);
        m = fmaxf(m, __shfl_xor(m, 1));
        m = fmaxf(m, __shfl_xor(m, 2));
        float l = 0.f;
        for (int kk = sub; kk < CHUNK; kk += 4){
            float e = __expf(s32[hq*130 + kk] - m);
            l += e;
            pbf[(h*16+qq)*136 + kk] = f2bf(e);
        }
        l += __shfl_xor(l, 1);
        l += __shfl_xor(l, 2);
        if (sub == 0) ml[hq] = make_float2(m, l);
    }
    __syncthreads();

    #pragma unroll
    for (int j=0;j<15;++j){
        int i = tid + j*512;
        int kk = i >> 6, dp = (i & 63)*2;
        unsigned u = vreg[j];
        vt[dp*136 + kk]     = (ushort_t)(u & 0xFFFF);
        vt[(dp+1)*136 + kk] = (ushort_t)(u >> 16);
    }
    if (tid < 320){
        int i = tid + 7680;
        int kk = i >> 6, dp = (i & 63)*2;
        unsigned u = vreg[15];
        vt[dp*136 + kk]     = (ushort_t)(u & 0xFFFF);
        vt[(dp+1)*136 + kk] = (ushort_t)(u >> 16);
    }
    if (tid < 384){
        int dp = tid / 3, kk = 125 + tid % 3;
        vt[dp*136 + kk] = 0;
    }
    __syncthreads();

    {
        int h = w >> 1;
        f32x4 acc = (f32x4){0,0,0,0};
        #pragma unroll
        for (int kc=0; kc<4; ++kc){
            short8 pf = *(const short8*)&pbf[(h*16+lr)*136 + kc*32 + hi8];
            short8 vf = *(const short8*)&vt[(w*16+lr)*136 + kc*32 + hi8];
            acc = __builtin_amdgcn_mfma_f32_16x16x32_bf16(pf, vf, acc, 0, 0, 0);
        }
        int qbase = (lane>>4)*4;
        float* ob = opart + ((size_t)(b*NSPLIT+sp)*12)*128;
        #pragma unroll
        for (int r=0; r<4; ++r){
            int qq = qbase + r;
            if (qq < 12) ob[(size_t)qq*128 + w*16 + lr] = acc[r];
        }
    }
    if (tid < 48) mlpart[(size_t)(b*NSPLIT+sp)*48 + tid] = ml[tid];
}

__global__ __launch_bounds__(256) void cross_attn_comb(const float* __restrict__ opart,
        const float* __restrict__ mlpart, ushort_t* __restrict__ attbf){
    int b = blockIdx.x, tid = threadIdx.x;
    __shared__ float mls[NSPLIT*48*2];
    for (int i = tid; i < NSPLIT*48*2; i += 256) mls[i] = mlpart[(size_t)b*NSPLIT*96 + i];
    __syncthreads();
    for (int p = tid; p < 1536; p += 256){
        int qq = p >> 7, dp = p & 127, h = dp >> 5, hq = h*12 + qq;
        float M = -1e30f;
        #pragma unroll
        for (int sp=0; sp<NSPLIT; ++sp) M = fmaxf(M, mls[sp*96 + hq*2]);
        float L = 0.f, O = 0.f;
        #pragma unroll
        for (int sp=0; sp<NSPLIT; ++sp){
            float wgt = __expf(mls[sp*96 + hq*2] - M);
            L += wgt * mls[sp*96 + hq*2 + 1];
            O += wgt * opart[((size_t)(b*NSPLIT+sp)*12 + qq)*128 + dp];
        }
        attbf[((size_t)b*12 + qq)*128 + dp] = f2bf(O / L);
    }
}

__global__ __launch_bounds__(256) void final_out(const float* __restrict__ t,
        const float* __restrict__ lw, const float* __restrict__ lb,
        const float* __restrict__ ow, const float* __restrict__ ob, float* __restrict__ out){
    int r = blockIdx.x*4 + (threadIdx.x>>6);
    int lane = threadIdx.x & 63;
    const float2* x2 = (const float2*)(t + (size_t)r*128);
    float2 v = x2[lane];
    float s = v.x+v.y;
    for (int o=32;o>0;o>>=1) s += __shfl_xor(s,o);
    float mean = s*(1.f/128.f);
    float dx=v.x-mean, dy=v.y-mean;
    float var = dx*dx+dy*dy;
    for (int o=32;o>0;o>>=1) var += __shfl_xor(var,o);
    float rs = rsqrtf(var*(1.f/128.f)+1e-5f);
    float2 w2=((const float2*)lw)[lane], b2=((const float2*)lb)[lane];
    float2 o2=((const float2*)ow)[lane];
    float d = (dx*rs*w2.x+b2.x)*o2.x + (dy*rs*w2.y+b2.y)*o2.y;
    for (int o=32;o>0;o>>=1) d += __shfl_xor(d,o);
    if (lane==0) out[r] = d + ob[0];
}

extern "C" void kernel_launch(void* const* d_in, const int* in_sizes, int n_in,
                              void* d_out, int out_size, void* d_ws, size_t ws_size,
                              hipStream_t stream){
    (void)in_sizes; (void)n_in; (void)out_size; (void)ws_size;
    const float* x        = (const float*)d_in[0];
    const int*   eidx     = (const int*)d_in[1];
    const float* in_w     = (const float*)d_in[3];
    const float* in_b     = (const float*)d_in[4];
    const float* gcn_w    = (const float*)d_in[5];
    const float* gcn_b    = (const float*)d_in[6];
    const float* ln_w     = (const float*)d_in[7];
    const float* ln_b     = (const float*)d_in[8];
    const float* cq       = (const float*)d_in[9];
    const float* sa_qkv_w = (const float*)d_in[10];
    const float* sa_qkv_b = (const float*)d_in[11];
    const float* sa_out_w = (const float*)d_in[12];
    const float* sa_out_b = (const float*)d_in[13];
    const float* ca_qkv_w = (const float*)d_in[14];
    const float* ca_qkv_b = (const float*)d_in[15];
    const float* ca_out_w = (const float*)d_in[16];
    const float* ca_out_b = (const float*)d_in[17];
    const float* n1w=(const float*)d_in[18]; const float* n1b=(const float*)d_in[19];
    const float* n2w=(const float*)d_in[20]; const float* n2b=(const float*)d_in[21];
    const float* n3w=(const float*)d_in[22]; const float* n3b=(const float*)d_in[23];
    const float* ff1w=(const float*)d_in[24]; const float* ff1b=(const float*)d_in[25];
    const float* ff2w=(const float*)d_in[26]; const float* ff2b=(const float*)d_in[27];
    const float* opln_w=(const float*)d_in[28]; const float* opln_b=(const float*)d_in[29];
    const float* opw=(const float*)d_in[30]; const float* opb=(const float*)d_in[31];
    float* out = (float*)d_out;

    char* base = (char*)d_ws;
    size_t off = 0;
    auto alloc = [&](size_t bytes)->void*{
        void* r = base + off; off += (bytes + 255) & ~(size_t)255; return r;
    };
    ushort_t* hbf   = (ushort_t*)alloc((size_t)NNODES*DD*2);
    ushort_t* kbf   = (ushort_t*)alloc((size_t)NNODES*DD*2);  // also hwbf during GCN loop
    ushort_t* vbf   = (ushort_t*)alloc((size_t)NNODES*DD*2);
    ushort_t* Wb    = (ushort_t*)alloc((size_t)5*DD*DD*2);
    ushort_t* Wpad  = (ushort_t*)alloc((size_t)DD*32*2);
    ushort_t* Wdec  = (ushort_t*)alloc((size_t)147456*2);
    float*    dinv  = (float*)alloc((size_t)NNODES*4);
    int*      cnt   = (int*)  alloc((size_t)NNODES*4);
    int*      offs  = (int*)  alloc((size_t)(NNODES+1)*4);
    int*      bsum  = (int*)  alloc(512*4);
    int2*     ee    = (int2*) alloc((size_t)NEDGES*8);
    float*    t12   = (float*)alloc((size_t)12*DD*4);
    float*    tn12  = (float*)alloc((size_t)12*DD*4);
    float*    sq12  = (float*)alloc((size_t)12*384*4);
    float*    att12 = (float*)alloc((size_t)12*DD*4);
    float*    q12   = (float*)alloc((size_t)12*DD*4);
    float*    tfull = (float*)alloc((size_t)NROWS*DD*4);
    ushort_t* tnbf  = (ushort_t*)alloc((size_t)NROWS*DD*2);
    ushort_t* attbf = (ushort_t*)alloc((size_t)NROWS*DD*2);
    ushort_t* ffhbf = (ushort_t*)alloc((size_t)NROWS*512*2);
    float*    opart = (float*)alloc((size_t)BB*NSPLIT*12*128*4);
    float2*   mlprt = (float2*)alloc((size_t)BB*NSPLIT*48*8);
    ushort_t* hwbf  = kbf;

    const int* erow = eidx;
    const int* ecol = eidx + NEDGES;

    // CSR build (once, reused by all 3 GCN layers)
    hipMemsetAsync(cnt, 0, (size_t)NNODES*4, stream);
    count_edges<<<NEDGES/256, 256, 0, stream>>>(ecol, cnt);
    scan_a<<<NNODES/256, 256, 0, stream>>>(cnt, offs, bsum, dinv);
    scan_b<<<1, 512, 0, stream>>>(bsum, NNODES/256);
    scan_c<<<NNODES/256, 256, 0, stream>>>(offs, bsum);
    hipMemsetAsync(cnt, 0, (size_t)NNODES*4, stream);
    fill_csr<<<NEDGES/256, 256, 0, stream>>>(erow, ecol, offs, cnt, dinv, ee);

    conv_all<<<912, 256, 0, stream>>>(gcn_w, ca_qkv_w, in_w, ca_out_w, ff1w, ff2w, Wb, Wpad, Wdec);

    // node pipeline (residual lives in hbf as bf16)
    in_proj_gemm0<<<NNODES/64, 256, 0, stream>>>(x, Wpad, in_b, Wb, hbf, hwbf);
    gcn_agg<<<NNODES/16, 256, 0, stream>>>(hbf, hwbf, offs, ee, dinv,
            gcn_b, ln_w, ln_b, 0);
    for (int i=1;i<3;++i){
        gemm_mfma<<<NNODES/64, 256, 0, stream>>>(hbf, Wb + (size_t)i*DD*DD, nullptr, hwbf);
        gcn_agg<<<NNODES/16, 256, 0, stream>>>(hbf, hwbf, offs, ee, dinv,
                gcn_b + (size_t)i*DD, ln_w + (size_t)i*DD, ln_b + (size_t)i*DD, i==2);
    }
    // fused cross-attn K+V projections (A read once)
    gemm_mfma_kv<<<NNODES/64, 256, 0, stream>>>(hbf, Wb + (size_t)3*DD*DD, Wb + (size_t)4*DD*DD,
            ca_qkv_b + DD, ca_qkv_b + 2*DD, kbf, vbf);

    // ---- decoder: batch-invariant 12-row prefix (fp32, exact, multi-launch) ----
    ln_rows<<<3, 256, 0, stream>>>(cq, tn12, n1w, n1b);
    small_gemm<<<18, 256, 0, stream>>>(tn12, sa_qkv_w, sa_qkv_b, sq12, nullptr, 12, 128, 384, 0);
    self_attn12<<<4, 64, 0, stream>>>(sq12, att12);
    small_gemm<<<6, 256, 0, stream>>>(att12, sa_out_w, sa_out_b, t12, cq, 12, 128, 128, 0);
    ln_rows<<<3, 256, 0, stream>>>(t12, tn12, n2w, n2b);
    small_gemm<<<6, 256, 0, stream>>>(tn12, ca_qkv_w, ca_qkv_b, q12, nullptr, 12, 128, 128, 0);

    // ---- per-batch: cross-attention + FF (bf16 MFMA) ----
    cross_attn_part<<<BB*NSPLIT, 512, 0, stream>>>(q12, kbf, vbf, opart, mlprt);
    cross_attn_comb<<<BB, 256, 0, stream>>>(opart, (const float*)mlprt, attbf);
    dim3 g24_1(24,1), g24_4(24,4);
    dec_gemm<<<g24_1, 256, 0, stream>>>(attbf, Wdec, ca_out_b, tfull, nullptr, t12, 128, 128, 16|8);
    ln_rows_bf<<<NROWS/4, 256, 0, stream>>>(tfull, tnbf, n3w, n3b);
    dec_gemm<<<g24_4, 256, 0, stream>>>(tnbf, Wdec + 16384, ff1b, nullptr, ffhbf, nullptr, 128, 512, 2|4);
    dec_gemm<<<g24_1, 256, 0, stream>>>(ffhbf, Wdec + 81920, ff2b, tfull, nullptr, nullptr, 512, 128, 1|8);
    final_out<<<NROWS/4, 256, 0, stream>>>(tfull, opln_w, opln_b, opw, opb, out);
}